// Round 10
// baseline (431.810 us; speedup 1.0000x reference)
//
#include <hip/hip_runtime.h>
#include <math.h>

#define GSZ 256

typedef unsigned short u16;
typedef short bf16x8 __attribute__((ext_vector_type(8)));
typedef u16 u16x8 __attribute__((ext_vector_type(8)));
typedef float f32x4 __attribute__((ext_vector_type(4)));
#define MFMA16 __builtin_amdgcn_mfma_f32_16x16x32_bf16

// hF fragment layout: unit(n,c) = hF + (((n>>5)*NCC + (c>>4))*64 + ((n>>3)&3)*16 + (c&15))*8,
// elem n&7.  NCC = 128 for h (2048 cols), 8 for EqkF (128 cols).

__device__ __forceinline__ float bf2f(u16 u){
  union { unsigned int i; float f; } x; x.i = ((unsigned int)u) << 16; return x.f;
}
__device__ __forceinline__ u16 f2bf(float f){
  union { float ff; unsigned int i; } x; x.ff = f;
  unsigned int r = x.i + 0x7fffu + ((x.i >> 16) & 1u);
  return (u16)(r >> 16);
}
__device__ __forceinline__ float sigm(float x){ return 1.0f/(1.0f+__expf(-x)); }
__device__ __forceinline__ float siluf(float x){ return x/(1.0f+__expf(-x)); }

__device__ __forceinline__ void gload16(const void* g, void* l){
  __builtin_amdgcn_global_load_lds(
      (const __attribute__((address_space(1))) void*)g,
      (__attribute__((address_space(3))) void*)l, 16, 0, 0);
}

__device__ __forceinline__ float2 blockReduce2(float s, float ss){
  __shared__ float red[8];
  #pragma unroll
  for (int off=32; off>0; off>>=1){
    s  += __shfl_down(s, off, 64);
    ss += __shfl_down(ss, off, 64);
  }
  int lane = threadIdx.x & 63, wid = threadIdx.x >> 6;
  if (lane==0){ red[wid]=s; red[4+wid]=ss; }
  __syncthreads();
  float2 r;
  r.x = red[0]+red[1]+red[2]+red[3];
  r.y = red[4]+red[5]+red[6]+red[7];
  return r;
}

// ---------------- small prep kernels ----------------

__global__ __launch_bounds__(256) void shift_ln_kernel(
    const float* __restrict__ x, u16* __restrict__ out, int N)
{
  int n = blockIdx.x;
  int t = threadIdx.x;
  float v0 = (n > 0) ? x[(long long)(n-1)*512 + t] : 0.0f;
  float v1 = x[(long long)n*512 + 256 + t];
  float2 r = blockReduce2(v0+v1, fmaf(v0,v0,v1*v1));
  float mu = r.x * (1.0f/512.0f);
  float var = r.y * (1.0f/512.0f) - mu*mu;
  float rs = rsqrtf(var + 1e-5f);
  long long base = (long long)n*512;
  out[base + t]       = f2bf((v0-mu)*rs);
  out[base + 256 + t] = f2bf((v1-mu)*rs);
}

__global__ __launch_bounds__(256) void fuse_wT_kernel(
    const float* __restrict__ g, const float* __restrict__ w,
    u16* __restrict__ wT, int K, int Nn)
{
  __shared__ float sL[32][33];
  int k0 = blockIdx.x*32, n0 = blockIdx.y*32;
  int t = threadIdx.x;
  int r = t >> 3, cq = t & 7;
  float4 v = *(const float4*)(w + (size_t)(k0+r)*Nn + n0 + cq*4);
  float gg = g[k0+r];
  sL[r][cq*4+0] = v.x*gg; sL[r][cq*4+1] = v.y*gg;
  sL[r][cq*4+2] = v.z*gg; sL[r][cq*4+3] = v.w*gg;
  __syncthreads();
  ushort4 o;
  o.x = f2bf(sL[cq*4+0][r]); o.y = f2bf(sL[cq*4+1][r]);
  o.z = f2bf(sL[cq*4+2][r]); o.w = f2bf(sL[cq*4+3][r]);
  *(ushort4*)(wT + (size_t)(n0+r)*K + k0 + cq*4) = o;
}

__global__ void copy_bias_kernel(const float* __restrict__ bias, float* __restrict__ bout, int Nn){
  int i = blockIdx.x*256 + threadIdx.x;
  if (i < Nn) bout[i] = bias[i];
}

__global__ __launch_bounds__(256) void fuse_b_acc(
    const float* __restrict__ bln, const float* __restrict__ w,
    float* __restrict__ bout, int K, int Nn)
{
  int n = blockIdx.x*256 + threadIdx.x;
  int k0 = blockIdx.y*64;
  if (n >= Nn) return;
  float acc = 0.f;
  #pragma unroll
  for (int k = 0; k < 64; ++k)
    acc = fmaf(bln[k0+k], w[(size_t)(k0+k)*Nn + n], acc);
  atomicAdd(&bout[n], acc);
}

__global__ void zero_kernel(float* __restrict__ p, long long total){
  long long i = (long long)blockIdx.x*256 + threadIdx.x;
  if (i < total) p[i] = 0.0f;
}

// ---------------- MFMA kernels (chunk-linear LDS + global_load_lds) --------------
// LDS chunk = 64 units x 16B; unit l of chunk = fragment of lane l.
// MFMA frags: A row=l&15 k=(l>>4)*8+j ; B col=l&15 ; D col=l&15 row=(l>>4)*4+i.

// C = silu(A @ WT^T + bias).  BM=128, BN=128, BK=32, dbuf 2-barrier counted-vmcnt.
__global__ __launch_bounds__(256) void gemm_mfma_silu(
    const u16* __restrict__ A, int lda,
    const u16* __restrict__ BT, int ldbt, int wtc0,
    u16* __restrict__ C, int ldc,
    const float* __restrict__ bias, int K)
{
  __shared__ u16 lds[2*16*512];
  int t = threadIdx.x;
  int lane = t & 63, wid = t >> 6;
  int wm = wid >> 1, wn = wid & 1;
  int lrow = lane & 15, kcL = lane >> 4;
  int bm = blockIdx.y*128, bn = blockIdx.x*128;
  const u16* gA0 = A + (size_t)(bm + wid*16 + lrow)*lda + kcL*8;
  const u16* gA1 = A + (size_t)(bm + (wid+4)*16 + lrow)*lda + kcL*8;
  const u16* gB0 = BT + (size_t)(wtc0 + bn + wid*16 + lrow)*ldbt + kcL*8;
  const u16* gB1 = BT + (size_t)(wtc0 + bn + (wid+4)*16 + lrow)*ldbt + kcL*8;
  f32x4 acc[4][4] = {};
  int nt = K >> 5;
  {
    u16* b = lds;
    gload16(gA0, b + (size_t)wid*512);
    gload16(gA1, b + (size_t)(wid+4)*512);
    gload16(gB0, b + (size_t)(8+wid)*512);
    gload16(gB1, b + (size_t)(12+wid)*512);
  }
  int cur = 0;
  for (int ti = 0; ti < nt; ++ti) {
    if (ti + 1 < nt) {
      int k1 = (ti+1) << 5;
      u16* b = lds + (size_t)(cur^1)*8192;
      gload16(gA0 + k1, b + (size_t)wid*512);
      gload16(gA1 + k1, b + (size_t)(wid+4)*512);
      gload16(gB0 + k1, b + (size_t)(8+wid)*512);
      gload16(gB1 + k1, b + (size_t)(12+wid)*512);
      asm volatile("s_waitcnt vmcnt(4)" ::: "memory");
    } else {
      asm volatile("s_waitcnt vmcnt(0)" ::: "memory");
    }
    __builtin_amdgcn_s_barrier();
    asm volatile("" ::: "memory");
    const bf16x8* L = (const bf16x8*)(lds + (size_t)cur*8192);
    bf16x8 af[4], bfr[4];
    #pragma unroll
    for (int mr = 0; mr < 4; ++mr) af[mr] = L[(wm*4+mr)*64 + lane];
    #pragma unroll
    for (int nr = 0; nr < 4; ++nr) bfr[nr] = L[(8 + wn*4+nr)*64 + lane];
    #pragma unroll
    for (int mr = 0; mr < 4; ++mr)
      #pragma unroll
      for (int nr = 0; nr < 4; ++nr)
        acc[mr][nr] = MFMA16(af[mr], bfr[nr], acc[mr][nr], 0, 0, 0);
    asm volatile("" ::: "memory");
    __builtin_amdgcn_s_barrier();
    cur ^= 1;
  }
  #pragma unroll
  for (int mr = 0; mr < 4; ++mr)
    #pragma unroll
    for (int nr = 0; nr < 4; ++nr) {
      int col = bn + wn*64 + nr*16 + lrow;
      float bs = bias[wtc0 + col];
      #pragma unroll
      for (int i = 0; i < 4; ++i) {
        int row = bm + wm*64 + mr*16 + kcL*4 + i;
        C[(size_t)row*ldc + col] = f2bf(siluf(acc[mr][nr][i] + bs));
      }
    }
}

// attn = relu(Eq0 @ Ek2^T / GS)^2 per group — pure dbuf GEMM. grid (2, 2, G)
__global__ __launch_bounds__(256) void score_mfma2(
    const u16* __restrict__ Eq0, const u16* __restrict__ Ek2,
    u16* __restrict__ attn)
{
  __shared__ u16 lds[2*16*512];
  int t = threadIdx.x;
  int lane = t & 63, wid = t >> 6;
  int wm = wid >> 1, wn = wid & 1;
  int lrow = lane & 15, kcL = lane >> 4;
  int g = blockIdx.z;
  int bm = blockIdx.y*128, bn = blockIdx.x*128;
  size_t rowbase = (size_t)g * GSZ;
  const u16* gA0 = Eq0 + (rowbase + bm + wid*16 + lrow)*128 + kcL*8;
  const u16* gA1 = Eq0 + (rowbase + bm + (wid+4)*16 + lrow)*128 + kcL*8;
  const u16* gB0 = Ek2 + (rowbase + bn + wid*16 + lrow)*128 + kcL*8;
  const u16* gB1 = Ek2 + (rowbase + bn + (wid+4)*16 + lrow)*128 + kcL*8;
  f32x4 acc[4][4] = {};
  {
    u16* b = lds;
    gload16(gA0, b + (size_t)wid*512);
    gload16(gA1, b + (size_t)(wid+4)*512);
    gload16(gB0, b + (size_t)(8+wid)*512);
    gload16(gB1, b + (size_t)(12+wid)*512);
  }
  int cur = 0;
  for (int ti = 0; ti < 4; ++ti) {
    if (ti + 1 < 4) {
      int k1 = (ti+1) << 5;
      u16* b = lds + (size_t)(cur^1)*8192;
      gload16(gA0 + k1, b + (size_t)wid*512);
      gload16(gA1 + k1, b + (size_t)(wid+4)*512);
      gload16(gB0 + k1, b + (size_t)(8+wid)*512);
      gload16(gB1 + k1, b + (size_t)(12+wid)*512);
      asm volatile("s_waitcnt vmcnt(4)" ::: "memory");
    } else {
      asm volatile("s_waitcnt vmcnt(0)" ::: "memory");
    }
    __builtin_amdgcn_s_barrier();
    asm volatile("" ::: "memory");
    const bf16x8* L = (const bf16x8*)(lds + (size_t)cur*8192);
    bf16x8 af[4], bfr[4];
    #pragma unroll
    for (int mr = 0; mr < 4; ++mr) af[mr] = L[(wm*4+mr)*64 + lane];
    #pragma unroll
    for (int nr = 0; nr < 4; ++nr) bfr[nr] = L[(8 + wn*4+nr)*64 + lane];
    #pragma unroll
    for (int mr = 0; mr < 4; ++mr)
      #pragma unroll
      for (int nr = 0; nr < 4; ++nr)
        acc[mr][nr] = MFMA16(af[mr], bfr[nr], acc[mr][nr], 0, 0, 0);
    asm volatile("" ::: "memory");
    __builtin_amdgcn_s_barrier();
    cur ^= 1;
  }
  #pragma unroll
  for (int mr = 0; mr < 4; ++mr)
    #pragma unroll
    for (int nr = 0; nr < 4; ++nr) {
      int col = bn + wn*64 + nr*16 + lrow;
      #pragma unroll
      for (int i = 0; i < 4; ++i) {
        int row = bm + wm*64 + mr*16 + kcL*4 + i;
        float s = fmaxf(acc[mr][nr][i] * (1.0f/GSZ), 0.0f);
        attn[(rowbase + row)*GSZ + col] = f2bf(s*s);
      }
    }
}

// Fraw[d][e] += sum_n EqkF(n,d) * hF(n,e) — pure gload dbuf GEMM. grid (32, 16)
__global__ __launch_bounds__(256) void linkv_mfma(
    const u16* __restrict__ EqkF, const u16* __restrict__ hF,
    float* __restrict__ Fraw, int N)
{
  __shared__ u16 lds[2*12*512];   // per buf: A chunks 0..7 (128 d), B 8..11 (64 e)
  int t = threadIdx.x;
  int lane = t & 63, wid = t >> 6;
  int wm = wid >> 1, wn = wid & 1;
  int lrow = lane & 15, kcL = lane >> 4;
  int e0 = blockIdx.x * 64;
  int nkt = (N / gridDim.y) >> 5;                // 32
  size_t kt0 = (size_t)blockIdx.y * nkt;
  f32x4 acc[4][2] = {};
  auto issue = [&](int kt, u16* b) {
    size_t ktile = kt0 + kt;
    gload16(EqkF + ((ktile*8 + wid)*64 + lane)*8,           b + (size_t)wid*512);
    gload16(EqkF + ((ktile*8 + wid+4)*64 + lane)*8,         b + (size_t)(wid+4)*512);
    gload16(hF + ((ktile*128 + (e0>>4) + wid)*64 + lane)*8, b + (size_t)(8+wid)*512);
  };
  issue(0, lds);
  int cur = 0;
  for (int ti = 0; ti < nkt; ++ti) {
    if (ti + 1 < nkt) {
      issue(ti + 1, lds + (size_t)(cur^1)*6144);
      asm volatile("s_waitcnt vmcnt(3)" ::: "memory");
    } else {
      asm volatile("s_waitcnt vmcnt(0)" ::: "memory");
    }
    __builtin_amdgcn_s_barrier();
    asm volatile("" ::: "memory");
    const bf16x8* L = (const bf16x8*)(lds + (size_t)cur*6144);
    bf16x8 af[4], bfr[2];
    #pragma unroll
    for (int mr = 0; mr < 4; ++mr) af[mr] = L[(wm*4+mr)*64 + lane];
    #pragma unroll
    for (int nr = 0; nr < 2; ++nr) bfr[nr] = L[(8 + wn*2+nr)*64 + lane];
    #pragma unroll
    for (int mr = 0; mr < 4; ++mr)
      #pragma unroll
      for (int nr = 0; nr < 2; ++nr)
        acc[mr][nr] = MFMA16(af[mr], bfr[nr], acc[mr][nr], 0, 0, 0);
    asm volatile("" ::: "memory");
    __builtin_amdgcn_s_barrier();
    cur ^= 1;
  }
  #pragma unroll
  for (int mr = 0; mr < 4; ++mr)
    #pragma unroll
    for (int nr = 0; nr < 2; ++nr) {
      int e = e0 + wn*32 + nr*16 + lrow;
      #pragma unroll
      for (int i = 0; i < 4; ++i) {
        int d = wm*64 + mr*16 + kcL*4 + i;
        atomicAdd(&Fraw[(size_t)d*2048 + e], acc[mr][nr][i]);
      }
    }
}

// F = inv_n*(g3[d]*Fraw + b3[d]*hsum[e]); FTg[e][d] = g1[d]*F ; cvec[e] = sum_d b1[d]*F
__global__ __launch_bounds__(256) void fconv_kernel(
    const float* __restrict__ Fraw, const float* __restrict__ osg, const float* __restrict__ osb,
    const float* __restrict__ hsum, float inv_n,
    u16* __restrict__ FTg, float* __restrict__ cvec)
{
  __shared__ float g1s[128], b1s[128], g3s[128], b3s[128];
  int t = threadIdx.x;
  if (t < 128) { g1s[t] = osg[128+t]; b1s[t] = osb[128+t];
                 g3s[t] = osg[3*128+t]; b3s[t] = osb[3*128+t]; }
  __syncthreads();
  int e = blockIdx.x*256 + t;
  float hs = hsum[e];
  float c = 0.f;
  for (int d = 0; d < 128; ++d) {
    float f = inv_n * fmaf(g3s[d], Fraw[(size_t)d*2048 + e], b3s[d]*hs);
    c = fmaf(b1s[d], f, c);
    FTg[(size_t)e*128 + d] = f2bf(g1s[d] * f);
  }
  cvec[e] = c;
}

// fused quad+lin attention + gate. All operands gload16; 2-barrier dbuf counted vmcnt.
// BM=128, cols=64 (V,U). 12 tiles (8 quad + 4 lin). grid 2048, XCD swizzle.
__global__ __launch_bounds__(256) void quadlin_mfma(
    const u16* __restrict__ attn, const u16* __restrict__ hF,
    const u16* __restrict__ eqk, const u16* __restrict__ FTg,
    const float* __restrict__ cvec, u16* __restrict__ T2)
{
  __shared__ u16 lds[2*16*512];   // per buf: A 0..7, BV 8..11, BU 12..15
  int bid = blockIdx.x;
  int wgid = (bid & 7)*256 + (bid >> 3);   // bijective: 2048 = 8*256
  int g = wgid >> 5;
  int rem = wgid & 31;
  int bm = (rem >> 4) * 128;
  int cb = (rem & 15) * 64;
  int t = threadIdx.x;
  int lane = t & 63, wid = t >> 6;
  int wm = wid >> 1, wn = wid & 1;
  int lrow = lane & 15, kcL = lane >> 4;
  size_t rowbase = (size_t)g * GSZ;
  f32x4 accV[4][2] = {}, accU[4][2] = {};
  const u16* gA0q = attn + (rowbase + bm + wid*16 + lrow)*GSZ + kcL*8;
  const u16* gA1q = attn + (rowbase + bm + (wid+4)*16 + lrow)*GSZ + kcL*8;
  const u16* gA0l = eqk + (rowbase + bm + wid*16 + lrow)*128 + kcL*8;
  const u16* gA1l = eqk + (rowbase + bm + (wid+4)*16 + lrow)*128 + kcL*8;
  const u16* gBVl = FTg + (size_t)(cb + wid*16 + lrow)*128 + kcL*8;
  const u16* gBUl = FTg + (size_t)(1024 + cb + wid*16 + lrow)*128 + kcL*8;
  auto issue = [&](int ti, u16* b) {
    if (ti < 8) {
      int k0 = ti << 5;
      size_t ktile = (size_t)g*8 + ti;
      gload16(gA0q + k0, b + (size_t)wid*512);
      gload16(gA1q + k0, b + (size_t)(wid+4)*512);
      gload16(hF + ((ktile*128 + (cb>>4) + wid)*64 + lane)*8,      b + (size_t)(8+wid)*512);
      gload16(hF + ((ktile*128 + 64 + (cb>>4) + wid)*64 + lane)*8, b + (size_t)(12+wid)*512);
    } else {
      int k0 = (ti - 8) << 5;
      gload16(gA0l + k0, b + (size_t)wid*512);
      gload16(gA1l + k0, b + (size_t)(wid+4)*512);
      gload16(gBVl + k0, b + (size_t)(8+wid)*512);
      gload16(gBUl + k0, b + (size_t)(12+wid)*512);
    }
  };
  issue(0, lds);
  int cur = 0;
  for (int ti = 0; ti < 12; ++ti) {
    if (ti + 1 < 12) {
      issue(ti + 1, lds + (size_t)(cur^1)*8192);
      asm volatile("s_waitcnt vmcnt(4)" ::: "memory");
    } else {
      asm volatile("s_waitcnt vmcnt(0)" ::: "memory");
    }
    __builtin_amdgcn_s_barrier();
    asm volatile("" ::: "memory");
    const bf16x8* L = (const bf16x8*)(lds + (size_t)cur*8192);
    bf16x8 af[4], bv[2], bu[2];
    #pragma unroll
    for (int mr = 0; mr < 4; ++mr) af[mr] = L[(wm*4+mr)*64 + lane];
    #pragma unroll
    for (int nr = 0; nr < 2; ++nr) { bv[nr] = L[(8 + wn*2+nr)*64 + lane];
                                     bu[nr] = L[(12 + wn*2+nr)*64 + lane]; }
    #pragma unroll
    for (int mr = 0; mr < 4; ++mr)
      #pragma unroll
      for (int nr = 0; nr < 2; ++nr) {
        accV[mr][nr] = MFMA16(af[mr], bv[nr], accV[mr][nr], 0, 0, 0);
        accU[mr][nr] = MFMA16(af[mr], bu[nr], accU[mr][nr], 0, 0, 0);
      }
    asm volatile("" ::: "memory");
    __builtin_amdgcn_s_barrier();
    cur ^= 1;
  }
  // ---- epilogue: gate, v/u from hF units
  #pragma unroll
  for (int mr = 0; mr < 4; ++mr)
    #pragma unroll
    for (int nr = 0; nr < 2; ++nr) {
      int c = cb + wn*32 + nr*16 + lrow;
      float cV = cvec[c], cU = cvec[1024 + c];
      int np = bm + wm*64 + mr*16 + kcL*4;           // local n in group (0..255)
      size_t ktile = (size_t)g*8 + (np>>5);
      int lofs = ((np>>3)&3)*16 + (c&15);
      int eo = np & 7;                                // 0 or 4
      ushort4 vq = *(const ushort4*)(hF + ((ktile*128 + (c>>4))*64 + lofs)*8 + eo);
      ushort4 uq = *(const ushort4*)(hF + ((ktile*128 + 64 + (c>>4))*64 + lofs)*8 + eo);
      float vv[4] = {bf2f(vq.x), bf2f(vq.y), bf2f(vq.z), bf2f(vq.w)};
      float uu[4] = {bf2f(uq.x), bf2f(uq.y), bf2f(uq.z), bf2f(uq.w)};
      #pragma unroll
      for (int i = 0; i < 4; ++i) {
        float av = accV[mr][nr][i] + cV;
        float au = accU[mr][nr][i] + cU;
        T2[(rowbase + np + i)*1024 + c] = f2bf(au * vv[i] * sigm(av * uu[i]));
      }
    }
}

// ---------------- conv / norm kernels ----------------

// th-branch depthwise conv -> hF fragment layout + hsum atomics. grid (8, N/32)
__global__ __launch_bounds__(256) void dwconv_hf(
    const u16* __restrict__ xin, const float* __restrict__ kern,
    u16* __restrict__ hF, int colbase, float* __restrict__ hsum, int N)
{
  __shared__ float tile[48][64];
  __shared__ float psum[4][64];
  int c0 = blockIdx.x * 64;
  int n0 = blockIdx.y * 32;
  int t = threadIdx.x;
  int tx = t & 63, ty = t >> 6;
  #pragma unroll
  for (int it = 0; it < 3; ++it) {
    int idx = t + it*256;
    int r = idx >> 4, cq = (idx & 15)*4;
    int gn = n0 - 8 + r;
    float4 f;
    if (gn >= 0 && gn < N) {
      ushort4 q = *(const ushort4*)(xin + (size_t)gn*512 + c0 + cq);
      f.x = bf2f(q.x); f.y = bf2f(q.y); f.z = bf2f(q.z); f.w = bf2f(q.w);
    } else { f.x = 0.f; f.y = 0.f; f.z = 0.f; f.w = 0.f; }
    *(float4*)&tile[r][cq] = f;
  }
  __syncthreads();
  int chl = c0 + tx;
  float kr[17];
  #pragma unroll
  for (int k = 0; k < 17; ++k) kr[k] = kern[chl*17 + k];
  float vals[8], loc = 0.f;
  #pragma unroll
  for (int rr = 0; rr < 8; ++rr) {
    int r = ty*8 + rr;
    float s = 0.0f;
    #pragma unroll
    for (int k = 0; k < 17; ++k) s = fmaf(kr[k], tile[r+k][tx], s);
    vals[rr] = tile[r+8][tx] + s;
    loc += vals[rr];
  }
  int c = colbase + chl;
  u16x8 o;
  #pragma unroll
  for (int rr = 0; rr < 8; ++rr) o[rr] = f2bf(vals[rr]);
  *(u16x8*)(hF + ((((size_t)(n0>>5))*128 + (c>>4))*64 + ty*16 + (c&15))*8) = o;
  psum[ty][tx] = loc;
  __syncthreads();
  if (t < 64)
    atomicAdd(&hsum[c0 + t], psum[0][t]+psum[1][t]+psum[2][t]+psum[3][t]);
}

// qk dwconv: writes Eqk (row-major), Eq0, Ek2 (row-major), EqkF (fragment). grid (2, N/32)
__global__ __launch_bounds__(256) void dwconv_qk(
    const u16* __restrict__ xin, const float* __restrict__ kern,
    const float* __restrict__ osg, const float* __restrict__ osb,
    u16* __restrict__ Eqk, u16* __restrict__ Eq0, u16* __restrict__ Ek2,
    u16* __restrict__ EqkF, int N)
{
  __shared__ float tile[48][64];
  int c0 = blockIdx.x * 64;
  int n0 = blockIdx.y * 32;
  int t = threadIdx.x;
  int tx = t & 63, ty = t >> 6;
  #pragma unroll
  for (int it = 0; it < 3; ++it) {
    int idx = t + it*256;
    int r = idx >> 4, cq = (idx & 15)*4;
    int gn = n0 - 8 + r;
    float4 f;
    if (gn >= 0 && gn < N) {
      ushort4 q = *(const ushort4*)(xin + (size_t)gn*128 + c0 + cq);
      f.x = bf2f(q.x); f.y = bf2f(q.y); f.z = bf2f(q.z); f.w = bf2f(q.w);
    } else { f.x = 0.f; f.y = 0.f; f.z = 0.f; f.w = 0.f; }
    *(float4*)&tile[r][cq] = f;
  }
  __syncthreads();
  int ch = c0 + tx;
  float kr[17];
  #pragma unroll
  for (int k = 0; k < 17; ++k) kr[k] = kern[ch*17 + k];
  float g0 = osg[ch], b0 = osb[ch];
  float g2 = osg[2*128+ch], b2 = osb[2*128+ch];
  float vals[8];
  #pragma unroll
  for (int rr = 0; rr < 8; ++rr) {
    int r = ty*8 + rr;
    float s = 0.0f;
    #pragma unroll
    for (int k = 0; k < 17; ++k) s = fmaf(kr[k], tile[r+k][tx], s);
    vals[rr] = tile[r+8][tx] + s;
    size_t gi = (size_t)(n0 + r)*128 + ch;
    Eqk[gi] = f2bf(vals[rr]);
    Eq0[gi] = f2bf(fmaf(vals[rr], g0, b0));
    Ek2[gi] = f2bf(fmaf(vals[rr], g2, b2));
  }
  u16x8 o;
  #pragma unroll
  for (int rr = 0; rr < 8; ++rr) o[rr] = f2bf(vals[rr]);
  *(u16x8*)(EqkF + ((((size_t)(n0>>5))*8 + (ch>>4))*64 + ty*16 + (ch&15))*8) = o;
}

__global__ __launch_bounds__(256) void dwconv_final(
    const u16* __restrict__ xin, const float* __restrict__ kern,
    const float* __restrict__ resid, float* __restrict__ y, int N)
{
  __shared__ float tile[48][64];
  int c0 = blockIdx.x * 64;
  int n0 = blockIdx.y * 32;
  int t = threadIdx.x;
  int tx = t & 63, ty = t >> 6;
  #pragma unroll
  for (int it = 0; it < 3; ++it) {
    int idx = t + it*256;
    int r = idx >> 4, cq = (idx & 15)*4;
    int gn = n0 - 8 + r;
    float4 f;
    if (gn >= 0 && gn < N) {
      ushort4 q = *(const ushort4*)(xin + (size_t)gn*512 + c0 + cq);
      f.x = bf2f(q.x); f.y = bf2f(q.y); f.z = bf2f(q.z); f.w = bf2f(q.w);
    } else { f.x = 0.f; f.y = 0.f; f.z = 0.f; f.w = 0.f; }
    *(float4*)&tile[r][cq] = f;
  }
  __syncthreads();
  int ch = c0 + tx;
  float kr[17];
  #pragma unroll
  for (int k = 0; k < 17; ++k) kr[k] = kern[ch*17 + k];
  #pragma unroll
  for (int rr = 0; rr < 8; ++rr) {
    int r = ty*8 + rr;
    float s = 0.0f;
    #pragma unroll
    for (int k = 0; k < 17; ++k) s = fmaf(kr[k], tile[r+k][tx], s);
    size_t gi = (size_t)(n0 + r)*512 + ch;
    y[gi] = resid[gi] + tile[r+8][tx] + s;
  }
}

__global__ __launch_bounds__(256) void ln1024_kernel(u16* __restrict__ buf)
{
  long long n = blockIdx.x;
  ushort4* p = (ushort4*)(buf + n*1024) + threadIdx.x;
  ushort4 q = *p;
  float a = bf2f(q.x), b = bf2f(q.y), c = bf2f(q.z), d = bf2f(q.w);
  float s = a+b+c+d;
  float ss = fmaf(a,a, fmaf(b,b, fmaf(c,c, d*d)));
  float2 r = blockReduce2(s, ss);
  float mu = r.x * (1.0f/1024.0f);
  float var = r.y * (1.0f/1024.0f) - mu*mu;
  float rs = rsqrtf(var + 1e-5f);
  q.x = f2bf((a-mu)*rs); q.y = f2bf((b-mu)*rs);
  q.z = f2bf((c-mu)*rs); q.w = f2bf((d-mu)*rs);
  *p = q;
}

// ---------------- host launcher ----------------

extern "C" void kernel_launch(void* const* d_in, const int* in_sizes, int n_in,
                              void* d_out, int out_size, void* d_ws, size_t ws_size,
                              hipStream_t stream)
{
  const float* x        = (const float*)d_in[0];
  const float* th_ln_g  = (const float*)d_in[2];
  const float* th_ln_b  = (const float*)d_in[3];
  const float* th_w     = (const float*)d_in[4];
  const float* th_b     = (const float*)d_in[5];
  const float* th_conv  = (const float*)d_in[6];
  const float* qk_ln_g  = (const float*)d_in[7];
  const float* qk_ln_b  = (const float*)d_in[8];
  const float* qk_w     = (const float*)d_in[9];
  const float* qk_b     = (const float*)d_in[10];
  const float* qk_conv  = (const float*)d_in[11];
  const float* osg      = (const float*)d_in[12];
  const float* osb      = (const float*)d_in[13];
  const float* out_ln_g = (const float*)d_in[14];
  const float* out_ln_b = (const float*)d_in[15];
  const float* out_w    = (const float*)d_in[16];
  const float* out_b    = (const float*)d_in[17];
  const float* out_conv = (const float*)d_in[18];

  const int N = in_sizes[0] / 512;          // 16384
  const float inv_n = 1.0f / (float)N;
  const int G = N / GSZ;                    // 64
  char* wsb = (char*)d_ws;

  // ---- workspace layout (bytes), lifetime-aliased ----
  size_t o_hF   = 0;                                    // hF bf16: N*2048 (fragment layout)
  size_t o_T2   = o_hF  + (size_t)N*2048*2;             // T2 bf16: N*1024 (nx aliases)
  size_t o_sc   = o_T2  + (size_t)N*1024*2;             // scratch bf16: N*512
                                                        //   [0, N*128)      EqkF, then attn (N*256)
                                                        //   [N*256, N*384)  Eq0
                                                        //   [N*384, N*512)  Ek2
  size_t o_eqk  = o_sc  + (size_t)N*512*2;              // Eqk bf16: N*128
  size_t o_dqk  = o_eqk + (size_t)N*128*2;              // Dqk bf16 N*128 (aliases Fraw/FTg/cvec)
  size_t dq_sz  = (size_t)N*128*2;                      // 4 MB
  size_t o_wth  = o_dqk + dq_sz;
  size_t o_wqk  = o_wth + (size_t)2048*512*2;           // WthT
  size_t o_wout = o_wqk + (size_t)128*512*2;            // WqkT
  size_t o_bth  = o_wout+ (size_t)1024*512*2;           // WoutT
  size_t o_bqk  = o_bth + 2048*4;
  size_t o_bout = o_bqk + 128*4;
  size_t o_hsum = o_bout + 512*4;                       // hsum fp32: 2048
  size_t required = o_hsum + 2048*4;
  if (ws_size < required) return;

  u16*   hF   = (u16*)(wsb + o_hF);
  u16*   T2   = (u16*)(wsb + o_T2);
  u16*   nx   = T2;                       // alias: nx dead before T2 written
  u16*   scC  = (u16*)(wsb + o_sc);
  u16*   EqkF = scC;                      // alias: dead before attn written
  u16*   Eq0  = scC + (size_t)N*256;
  u16*   Ek2  = scC + (size_t)N*384;
  u16*   Eqk  = (u16*)(wsb + o_eqk);
  u16*   Dqk  = (u16*)(wsb + o_dqk);
  float* Fraw = (float*)(wsb + o_dqk);                     // 1 MB
  u16*   FTg  = (u16*)(wsb + o_dqk + (size_t)128*2048*4);  // 0.5 MB
  float* cvec = (float*)(wsb + o_dqk + (size_t)128*2048*4 + (size_t)2048*128*2);
  u16*   WthT = (u16*)(wsb + o_wth);
  u16*   WqkT = (u16*)(wsb + o_wqk);
  u16*   WoutT= (u16*)(wsb + o_wout);
  float* Bth  = (float*)(wsb + o_bth);
  float* Bqk  = (float*)(wsb + o_bqk);
  float* Bout = (float*)(wsb + o_bout);
  float* hsum = (float*)(wsb + o_hsum);

  // ---- weight prep + zeros ----
  hipLaunchKernelGGL(fuse_wT_kernel, dim3(16, 64), dim3(256), 0, stream, th_ln_g, th_w, WthT, 512, 2048);
  hipLaunchKernelGGL(fuse_wT_kernel, dim3(16, 4),  dim3(256), 0, stream, qk_ln_g, qk_w, WqkT, 512, 128);
  hipLaunchKernelGGL(fuse_wT_kernel, dim3(32, 16), dim3(256), 0, stream, out_ln_g, out_w, WoutT, 1024, 512);
  hipLaunchKernelGGL(copy_bias_kernel, dim3(8), dim3(256), 0, stream, th_b, Bth, 2048);
  hipLaunchKernelGGL(copy_bias_kernel, dim3(1), dim3(256), 0, stream, qk_b, Bqk, 128);
  hipLaunchKernelGGL(copy_bias_kernel, dim3(2), dim3(256), 0, stream, out_b, Bout, 512);
  hipLaunchKernelGGL(fuse_b_acc, dim3(8, 8),  dim3(256), 0, stream, th_ln_b,  th_w,  Bth, 512, 2048);
  hipLaunchKernelGGL(fuse_b_acc, dim3(1, 8),  dim3(256), 0, stream, qk_ln_b,  qk_w,  Bqk, 512, 128);
  hipLaunchKernelGGL(fuse_b_acc, dim3(2, 16), dim3(256), 0, stream, out_ln_b, out_w, Bout, 1024, 512);
  hipLaunchKernelGGL(zero_kernel, dim3(8), dim3(256), 0, stream, hsum, 2048LL);

  // ---- token shift + LN core ----
  hipLaunchKernelGGL(shift_ln_kernel, dim3(N), dim3(256), 0, stream, x, nx, N);

  // ---- th branch, 4 column chunks of 512: GEMM -> scC, conv -> hF + hsum ----
  for (int ch = 0; ch < 4; ++ch) {
    hipLaunchKernelGGL(gemm_mfma_silu, dim3(4, N/128), dim3(256), 0, stream,
                       nx, 512, WthT, 512, ch*512, scC, 512, Bth, 512);
    hipLaunchKernelGGL(dwconv_hf, dim3(8, N/32), dim3(256), 0, stream,
                       scC, th_conv + (size_t)ch*512*17, hF, ch*512, hsum + ch*512, N);
  }

  // ---- qk branch: GEMM -> Dqk; conv -> Eqk + Eq0/Ek2 + EqkF ----
  hipLaunchKernelGGL(gemm_mfma_silu, dim3(1, N/128), dim3(256), 0, stream,
                     nx, 512, WqkT, 512, 0, Dqk, 128, Bqk, 512);
  hipLaunchKernelGGL(dwconv_qk, dim3(2, N/32), dim3(256), 0, stream,
                     Dqk, qk_conv, osg, osb, Eqk, Eq0, Ek2, EqkF, N);

  // ---- linear attention kv summary (pure gload GEMM) ----
  hipLaunchKernelGGL(zero_kernel, dim3(1024), dim3(256), 0, stream, Fraw, (long long)128*2048);
  hipLaunchKernelGGL(linkv_mfma, dim3(32, 16), dim3(256), 0, stream, EqkF, hF, Fraw, N);
  hipLaunchKernelGGL(fconv_kernel, dim3(8), dim3(256), 0, stream, Fraw, osg, osb, hsum, inv_n, FTg, cvec);

  // ---- quadratic attention scores (pure GEMM) -> scC[0, N*256) ----
  hipLaunchKernelGGL(score_mfma2, dim3(2, 2, G), dim3(256), 0, stream, Eq0, Ek2, scC);

  // ---- fused quad + lin + gate -> T2 ----
  hipLaunchKernelGGL(quadlin_mfma, dim3(2*G*16), dim3(256), 0, stream,
                     scC, hF, Eqk, FTg, cvec, T2);

  // ---- out branch ----
  hipLaunchKernelGGL(ln1024_kernel, dim3(N), dim3(256), 0, stream, T2);
  hipLaunchKernelGGL(gemm_mfma_silu, dim3(4, N/128), dim3(256), 0, stream,
                     T2, 1024, WoutT, 1024, 0, scC, 512, Bout, 1024);
  hipLaunchKernelGGL(dwconv_final, dim3(8, N/32), dim3(256), 0, stream,
                     scC, out_conv, x, (float*)d_out, N);
}

// Round 11
// 390.418 us; speedup vs baseline: 1.1060x; 1.1060x over previous
//
#include <hip/hip_runtime.h>
#include <math.h>

#define GSZ 256

typedef unsigned short u16;
typedef short bf16x8 __attribute__((ext_vector_type(8)));
typedef u16 u16x8 __attribute__((ext_vector_type(8)));
typedef float f32x4 __attribute__((ext_vector_type(4)));
#define MFMA16 __builtin_amdgcn_mfma_f32_16x16x32_bf16

// hF fragment layout: unit(n,c) = hF + (((n>>5)*NCC + (c>>4))*64 + ((n>>3)&3)*16 + (c&15))*8,
// elem n&7.  NCC = 128 for h (2048 cols), 8 for EqkF (128 cols).

__device__ __forceinline__ float bf2f(u16 u){
  union { unsigned int i; float f; } x; x.i = ((unsigned int)u) << 16; return x.f;
}
__device__ __forceinline__ u16 f2bf(float f){
  union { float ff; unsigned int i; } x; x.ff = f;
  unsigned int r = x.i + 0x7fffu + ((x.i >> 16) & 1u);
  return (u16)(r >> 16);
}
__device__ __forceinline__ float sigm(float x){ return 1.0f/(1.0f+__expf(-x)); }
__device__ __forceinline__ float siluf(float x){ return x/(1.0f+__expf(-x)); }

__device__ __forceinline__ void gload16(const void* g, void* l){
  __builtin_amdgcn_global_load_lds(
      (const __attribute__((address_space(1))) void*)g,
      (__attribute__((address_space(3))) void*)l, 16, 0, 0);
}

__device__ __forceinline__ float2 blockReduce2(float s, float ss){
  __shared__ float red[8];
  #pragma unroll
  for (int off=32; off>0; off>>=1){
    s  += __shfl_down(s, off, 64);
    ss += __shfl_down(ss, off, 64);
  }
  int lane = threadIdx.x & 63, wid = threadIdx.x >> 6;
  if (lane==0){ red[wid]=s; red[4+wid]=ss; }
  __syncthreads();
  float2 r;
  r.x = red[0]+red[1]+red[2]+red[3];
  r.y = red[4]+red[5]+red[6]+red[7];
  return r;
}

// ---------------- small prep kernels ----------------

__global__ __launch_bounds__(256) void shift_ln_kernel(
    const float* __restrict__ x, u16* __restrict__ out, int N)
{
  int n = blockIdx.x;
  int t = threadIdx.x;
  float v0 = (n > 0) ? x[(long long)(n-1)*512 + t] : 0.0f;
  float v1 = x[(long long)n*512 + 256 + t];
  float2 r = blockReduce2(v0+v1, fmaf(v0,v0,v1*v1));
  float mu = r.x * (1.0f/512.0f);
  float var = r.y * (1.0f/512.0f) - mu*mu;
  float rs = rsqrtf(var + 1e-5f);
  long long base = (long long)n*512;
  out[base + t]       = f2bf((v0-mu)*rs);
  out[base + 256 + t] = f2bf((v1-mu)*rs);
}

__global__ __launch_bounds__(256) void fuse_wT_kernel(
    const float* __restrict__ g, const float* __restrict__ w,
    u16* __restrict__ wT, int K, int Nn)
{
  __shared__ float sL[32][33];
  int k0 = blockIdx.x*32, n0 = blockIdx.y*32;
  int t = threadIdx.x;
  int r = t >> 3, cq = t & 7;
  float4 v = *(const float4*)(w + (size_t)(k0+r)*Nn + n0 + cq*4);
  float gg = g[k0+r];
  sL[r][cq*4+0] = v.x*gg; sL[r][cq*4+1] = v.y*gg;
  sL[r][cq*4+2] = v.z*gg; sL[r][cq*4+3] = v.w*gg;
  __syncthreads();
  ushort4 o;
  o.x = f2bf(sL[cq*4+0][r]); o.y = f2bf(sL[cq*4+1][r]);
  o.z = f2bf(sL[cq*4+2][r]); o.w = f2bf(sL[cq*4+3][r]);
  *(ushort4*)(wT + (size_t)(n0+r)*K + k0 + cq*4) = o;
}

__global__ void copy_bias_kernel(const float* __restrict__ bias, float* __restrict__ bout, int Nn){
  int i = blockIdx.x*256 + threadIdx.x;
  if (i < Nn) bout[i] = bias[i];
}

__global__ __launch_bounds__(256) void fuse_b_acc(
    const float* __restrict__ bln, const float* __restrict__ w,
    float* __restrict__ bout, int K, int Nn)
{
  int n = blockIdx.x*256 + threadIdx.x;
  int k0 = blockIdx.y*64;
  if (n >= Nn) return;
  float acc = 0.f;
  #pragma unroll
  for (int k = 0; k < 64; ++k)
    acc = fmaf(bln[k0+k], w[(size_t)(k0+k)*Nn + n], acc);
  atomicAdd(&bout[n], acc);
}

__global__ void zero_kernel(float* __restrict__ p, long long total){
  long long i = (long long)blockIdx.x*256 + threadIdx.x;
  if (i < total) p[i] = 0.0f;
}

// ---------------- MFMA kernels (chunk-linear LDS + global_load_lds) --------------
// LDS chunk = 64 units x 16B; unit l of chunk = fragment of lane l.
// MFMA frags: A row=l&15 k=(l>>4)*8+j ; B col=l&15 ; D col=l&15 row=(l>>4)*4+i.

// C = silu(A @ WT^T + bias).  BM=128, BN=128, BK=32, dbuf 2-barrier counted-vmcnt.
__global__ __launch_bounds__(256) void gemm_mfma_silu(
    const u16* __restrict__ A, int lda,
    const u16* __restrict__ BT, int ldbt, int wtc0,
    u16* __restrict__ C, int ldc,
    const float* __restrict__ bias, int K)
{
  __shared__ u16 lds[2*16*512];
  int t = threadIdx.x;
  int lane = t & 63, wid = t >> 6;
  int wm = wid >> 1, wn = wid & 1;
  int lrow = lane & 15, kcL = lane >> 4;
  int bm = blockIdx.y*128, bn = blockIdx.x*128;
  const u16* gA0 = A + (size_t)(bm + wid*16 + lrow)*lda + kcL*8;
  const u16* gA1 = A + (size_t)(bm + (wid+4)*16 + lrow)*lda + kcL*8;
  const u16* gB0 = BT + (size_t)(wtc0 + bn + wid*16 + lrow)*ldbt + kcL*8;
  const u16* gB1 = BT + (size_t)(wtc0 + bn + (wid+4)*16 + lrow)*ldbt + kcL*8;
  f32x4 acc[4][4] = {};
  int nt = K >> 5;
  {
    u16* b = lds;
    gload16(gA0, b + (size_t)wid*512);
    gload16(gA1, b + (size_t)(wid+4)*512);
    gload16(gB0, b + (size_t)(8+wid)*512);
    gload16(gB1, b + (size_t)(12+wid)*512);
  }
  int cur = 0;
  for (int ti = 0; ti < nt; ++ti) {
    if (ti + 1 < nt) {
      int k1 = (ti+1) << 5;
      u16* b = lds + (size_t)(cur^1)*8192;
      gload16(gA0 + k1, b + (size_t)wid*512);
      gload16(gA1 + k1, b + (size_t)(wid+4)*512);
      gload16(gB0 + k1, b + (size_t)(8+wid)*512);
      gload16(gB1 + k1, b + (size_t)(12+wid)*512);
      asm volatile("s_waitcnt vmcnt(4)" ::: "memory");
    } else {
      asm volatile("s_waitcnt vmcnt(0)" ::: "memory");
    }
    __builtin_amdgcn_s_barrier();
    asm volatile("" ::: "memory");
    const bf16x8* L = (const bf16x8*)(lds + (size_t)cur*8192);
    bf16x8 af[4], bfr[4];
    #pragma unroll
    for (int mr = 0; mr < 4; ++mr) af[mr] = L[(wm*4+mr)*64 + lane];
    #pragma unroll
    for (int nr = 0; nr < 4; ++nr) bfr[nr] = L[(8 + wn*4+nr)*64 + lane];
    #pragma unroll
    for (int mr = 0; mr < 4; ++mr)
      #pragma unroll
      for (int nr = 0; nr < 4; ++nr)
        acc[mr][nr] = MFMA16(af[mr], bfr[nr], acc[mr][nr], 0, 0, 0);
    asm volatile("" ::: "memory");
    __builtin_amdgcn_s_barrier();
    cur ^= 1;
  }
  #pragma unroll
  for (int mr = 0; mr < 4; ++mr)
    #pragma unroll
    for (int nr = 0; nr < 4; ++nr) {
      int col = bn + wn*64 + nr*16 + lrow;
      float bs = bias[wtc0 + col];
      #pragma unroll
      for (int i = 0; i < 4; ++i) {
        int row = bm + wm*64 + mr*16 + kcL*4 + i;
        C[(size_t)row*ldc + col] = f2bf(siluf(acc[mr][nr][i] + bs));
      }
    }
}

// attn = relu(Eq0 @ Ek2^T / GS)^2 per group — pure dbuf GEMM. grid (2, 2, G)
__global__ __launch_bounds__(256) void score_mfma2(
    const u16* __restrict__ Eq0, const u16* __restrict__ Ek2,
    u16* __restrict__ attn)
{
  __shared__ u16 lds[2*16*512];
  int t = threadIdx.x;
  int lane = t & 63, wid = t >> 6;
  int wm = wid >> 1, wn = wid & 1;
  int lrow = lane & 15, kcL = lane >> 4;
  int g = blockIdx.z;
  int bm = blockIdx.y*128, bn = blockIdx.x*128;
  size_t rowbase = (size_t)g * GSZ;
  const u16* gA0 = Eq0 + (rowbase + bm + wid*16 + lrow)*128 + kcL*8;
  const u16* gA1 = Eq0 + (rowbase + bm + (wid+4)*16 + lrow)*128 + kcL*8;
  const u16* gB0 = Ek2 + (rowbase + bn + wid*16 + lrow)*128 + kcL*8;
  const u16* gB1 = Ek2 + (rowbase + bn + (wid+4)*16 + lrow)*128 + kcL*8;
  f32x4 acc[4][4] = {};
  {
    u16* b = lds;
    gload16(gA0, b + (size_t)wid*512);
    gload16(gA1, b + (size_t)(wid+4)*512);
    gload16(gB0, b + (size_t)(8+wid)*512);
    gload16(gB1, b + (size_t)(12+wid)*512);
  }
  int cur = 0;
  for (int ti = 0; ti < 4; ++ti) {
    if (ti + 1 < 4) {
      int k1 = (ti+1) << 5;
      u16* b = lds + (size_t)(cur^1)*8192;
      gload16(gA0 + k1, b + (size_t)wid*512);
      gload16(gA1 + k1, b + (size_t)(wid+4)*512);
      gload16(gB0 + k1, b + (size_t)(8+wid)*512);
      gload16(gB1 + k1, b + (size_t)(12+wid)*512);
      asm volatile("s_waitcnt vmcnt(4)" ::: "memory");
    } else {
      asm volatile("s_waitcnt vmcnt(0)" ::: "memory");
    }
    __builtin_amdgcn_s_barrier();
    asm volatile("" ::: "memory");
    const bf16x8* L = (const bf16x8*)(lds + (size_t)cur*8192);
    bf16x8 af[4], bfr[4];
    #pragma unroll
    for (int mr = 0; mr < 4; ++mr) af[mr] = L[(wm*4+mr)*64 + lane];
    #pragma unroll
    for (int nr = 0; nr < 4; ++nr) bfr[nr] = L[(8 + wn*4+nr)*64 + lane];
    #pragma unroll
    for (int mr = 0; mr < 4; ++mr)
      #pragma unroll
      for (int nr = 0; nr < 4; ++nr)
        acc[mr][nr] = MFMA16(af[mr], bfr[nr], acc[mr][nr], 0, 0, 0);
    asm volatile("" ::: "memory");
    __builtin_amdgcn_s_barrier();
    cur ^= 1;
  }
  #pragma unroll
  for (int mr = 0; mr < 4; ++mr)
    #pragma unroll
    for (int nr = 0; nr < 4; ++nr) {
      int col = bn + wn*64 + nr*16 + lrow;
      #pragma unroll
      for (int i = 0; i < 4; ++i) {
        int row = bm + wm*64 + mr*16 + kcL*4 + i;
        float s = fmaxf(acc[mr][nr][i] * (1.0f/GSZ), 0.0f);
        attn[(rowbase + row)*GSZ + col] = f2bf(s*s);
      }
    }
}

// Fraw[d][e] += sum_n EqkF(n,d) * hF(n,e) — pure gload dbuf GEMM. grid (32, 16)
__global__ __launch_bounds__(256) void linkv_mfma(
    const u16* __restrict__ EqkF, const u16* __restrict__ hF,
    float* __restrict__ Fraw, int N)
{
  __shared__ u16 lds[2*12*512];
  int t = threadIdx.x;
  int lane = t & 63, wid = t >> 6;
  int wm = wid >> 1, wn = wid & 1;
  int lrow = lane & 15, kcL = lane >> 4;
  int e0 = blockIdx.x * 64;
  int nkt = (N / gridDim.y) >> 5;
  size_t kt0 = (size_t)blockIdx.y * nkt;
  f32x4 acc[4][2] = {};
  auto issue = [&](int kt, u16* b) {
    size_t ktile = kt0 + kt;
    gload16(EqkF + ((ktile*8 + wid)*64 + lane)*8,           b + (size_t)wid*512);
    gload16(EqkF + ((ktile*8 + wid+4)*64 + lane)*8,         b + (size_t)(wid+4)*512);
    gload16(hF + ((ktile*128 + (e0>>4) + wid)*64 + lane)*8, b + (size_t)(8+wid)*512);
  };
  issue(0, lds);
  int cur = 0;
  for (int ti = 0; ti < nkt; ++ti) {
    if (ti + 1 < nkt) {
      issue(ti + 1, lds + (size_t)(cur^1)*6144);
      asm volatile("s_waitcnt vmcnt(3)" ::: "memory");
    } else {
      asm volatile("s_waitcnt vmcnt(0)" ::: "memory");
    }
    __builtin_amdgcn_s_barrier();
    asm volatile("" ::: "memory");
    const bf16x8* L = (const bf16x8*)(lds + (size_t)cur*6144);
    bf16x8 af[4], bfr[2];
    #pragma unroll
    for (int mr = 0; mr < 4; ++mr) af[mr] = L[(wm*4+mr)*64 + lane];
    #pragma unroll
    for (int nr = 0; nr < 2; ++nr) bfr[nr] = L[(8 + wn*2+nr)*64 + lane];
    #pragma unroll
    for (int mr = 0; mr < 4; ++mr)
      #pragma unroll
      for (int nr = 0; nr < 2; ++nr)
        acc[mr][nr] = MFMA16(af[mr], bfr[nr], acc[mr][nr], 0, 0, 0);
    asm volatile("" ::: "memory");
    __builtin_amdgcn_s_barrier();
    cur ^= 1;
  }
  #pragma unroll
  for (int mr = 0; mr < 4; ++mr)
    #pragma unroll
    for (int nr = 0; nr < 2; ++nr) {
      int e = e0 + wn*32 + nr*16 + lrow;
      #pragma unroll
      for (int i = 0; i < 4; ++i) {
        int d = wm*64 + mr*16 + kcL*4 + i;
        atomicAdd(&Fraw[(size_t)d*2048 + e], acc[mr][nr][i]);
      }
    }
}

// F = inv_n*(g3[d]*Fraw + b3[d]*hsum[e]); FTg[e][d] = g1[d]*F ; cvec[e] = sum_d b1[d]*F
__global__ __launch_bounds__(256) void fconv_kernel(
    const float* __restrict__ Fraw, const float* __restrict__ osg, const float* __restrict__ osb,
    const float* __restrict__ hsum, float inv_n,
    u16* __restrict__ FTg, float* __restrict__ cvec)
{
  __shared__ float g1s[128], b1s[128], g3s[128], b3s[128];
  int t = threadIdx.x;
  if (t < 128) { g1s[t] = osg[128+t]; b1s[t] = osb[128+t];
                 g3s[t] = osg[3*128+t]; b3s[t] = osb[3*128+t]; }
  __syncthreads();
  int e = blockIdx.x*256 + t;
  float hs = hsum[e];
  float c = 0.f;
  for (int d = 0; d < 128; ++d) {
    float f = inv_n * fmaf(g3s[d], Fraw[(size_t)d*2048 + e], b3s[d]*hs);
    c = fmaf(b1s[d], f, c);
    FTg[(size_t)e*128 + d] = f2bf(g1s[d] * f);
  }
  cvec[e] = c;
}

// fused quad+lin attention + gate. All operands gload16; dbuf counted vmcnt. grid 2048.
__global__ __launch_bounds__(256) void quadlin_mfma(
    const u16* __restrict__ attn, const u16* __restrict__ hF,
    const u16* __restrict__ eqk, const u16* __restrict__ FTg,
    const float* __restrict__ cvec, u16* __restrict__ T2)
{
  __shared__ u16 lds[2*16*512];
  int bid = blockIdx.x;
  int wgid = (bid & 7)*256 + (bid >> 3);
  int g = wgid >> 5;
  int rem = wgid & 31;
  int bm = (rem >> 4) * 128;
  int cb = (rem & 15) * 64;
  int t = threadIdx.x;
  int lane = t & 63, wid = t >> 6;
  int wm = wid >> 1, wn = wid & 1;
  int lrow = lane & 15, kcL = lane >> 4;
  size_t rowbase = (size_t)g * GSZ;
  f32x4 accV[4][2] = {}, accU[4][2] = {};
  const u16* gA0q = attn + (rowbase + bm + wid*16 + lrow)*GSZ + kcL*8;
  const u16* gA1q = attn + (rowbase + bm + (wid+4)*16 + lrow)*GSZ + kcL*8;
  const u16* gA0l = eqk + (rowbase + bm + wid*16 + lrow)*128 + kcL*8;
  const u16* gA1l = eqk + (rowbase + bm + (wid+4)*16 + lrow)*128 + kcL*8;
  const u16* gBVl = FTg + (size_t)(cb + wid*16 + lrow)*128 + kcL*8;
  const u16* gBUl = FTg + (size_t)(1024 + cb + wid*16 + lrow)*128 + kcL*8;
  auto issue = [&](int ti, u16* b) {
    if (ti < 8) {
      int k0 = ti << 5;
      size_t ktile = (size_t)g*8 + ti;
      gload16(gA0q + k0, b + (size_t)wid*512);
      gload16(gA1q + k0, b + (size_t)(wid+4)*512);
      gload16(hF + ((ktile*128 + (cb>>4) + wid)*64 + lane)*8,      b + (size_t)(8+wid)*512);
      gload16(hF + ((ktile*128 + 64 + (cb>>4) + wid)*64 + lane)*8, b + (size_t)(12+wid)*512);
    } else {
      int k0 = (ti - 8) << 5;
      gload16(gA0l + k0, b + (size_t)wid*512);
      gload16(gA1l + k0, b + (size_t)(wid+4)*512);
      gload16(gBVl + k0, b + (size_t)(8+wid)*512);
      gload16(gBUl + k0, b + (size_t)(12+wid)*512);
    }
  };
  issue(0, lds);
  int cur = 0;
  for (int ti = 0; ti < 12; ++ti) {
    if (ti + 1 < 12) {
      issue(ti + 1, lds + (size_t)(cur^1)*8192);
      asm volatile("s_waitcnt vmcnt(4)" ::: "memory");
    } else {
      asm volatile("s_waitcnt vmcnt(0)" ::: "memory");
    }
    __builtin_amdgcn_s_barrier();
    asm volatile("" ::: "memory");
    const bf16x8* L = (const bf16x8*)(lds + (size_t)cur*8192);
    bf16x8 af[4], bv[2], bu[2];
    #pragma unroll
    for (int mr = 0; mr < 4; ++mr) af[mr] = L[(wm*4+mr)*64 + lane];
    #pragma unroll
    for (int nr = 0; nr < 2; ++nr) { bv[nr] = L[(8 + wn*2+nr)*64 + lane];
                                     bu[nr] = L[(12 + wn*2+nr)*64 + lane]; }
    #pragma unroll
    for (int mr = 0; mr < 4; ++mr)
      #pragma unroll
      for (int nr = 0; nr < 2; ++nr) {
        accV[mr][nr] = MFMA16(af[mr], bv[nr], accV[mr][nr], 0, 0, 0);
        accU[mr][nr] = MFMA16(af[mr], bu[nr], accU[mr][nr], 0, 0, 0);
      }
    asm volatile("" ::: "memory");
    __builtin_amdgcn_s_barrier();
    cur ^= 1;
  }
  #pragma unroll
  for (int mr = 0; mr < 4; ++mr)
    #pragma unroll
    for (int nr = 0; nr < 2; ++nr) {
      int c = cb + wn*32 + nr*16 + lrow;
      float cV = cvec[c], cU = cvec[1024 + c];
      int np = bm + wm*64 + mr*16 + kcL*4;
      size_t ktile = (size_t)g*8 + (np>>5);
      int lofs = ((np>>3)&3)*16 + (c&15);
      int eo = np & 7;
      ushort4 vq = *(const ushort4*)(hF + ((ktile*128 + (c>>4))*64 + lofs)*8 + eo);
      ushort4 uq = *(const ushort4*)(hF + ((ktile*128 + 64 + (c>>4))*64 + lofs)*8 + eo);
      float vv[4] = {bf2f(vq.x), bf2f(vq.y), bf2f(vq.z), bf2f(vq.w)};
      float uu[4] = {bf2f(uq.x), bf2f(uq.y), bf2f(uq.z), bf2f(uq.w)};
      #pragma unroll
      for (int i = 0; i < 4; ++i) {
        float av = accV[mr][nr][i] + cV;
        float au = accU[mr][nr][i] + cU;
        T2[(rowbase + np + i)*1024 + c] = f2bf(au * vv[i] * sigm(av * uu[i]));
      }
    }
}

// ---------------- conv / norm kernels ----------------

// th-branch depthwise conv, 64-row tiles -> hF + hsum. grid (cols/64, N/64)
__global__ __launch_bounds__(256) void dwconv_hf64(
    const u16* __restrict__ xin, int ldin, const float* __restrict__ kern,
    u16* __restrict__ hF, int colbase, float* __restrict__ hsum, int N)
{
  __shared__ float tile[80][64];
  __shared__ float psum[4][64];
  int c0 = blockIdx.x * 64;
  int n0 = blockIdx.y * 64;
  int t = threadIdx.x;
  int tx = t & 63, ty = t >> 6;
  #pragma unroll
  for (int it = 0; it < 5; ++it) {
    int idx = t + it*256;
    int r = idx >> 4, cq = (idx & 15)*4;
    int gn = n0 - 8 + r;
    float4 f;
    if (gn >= 0 && gn < N) {
      ushort4 q = *(const ushort4*)(xin + (size_t)gn*ldin + c0 + cq);
      f.x = bf2f(q.x); f.y = bf2f(q.y); f.z = bf2f(q.z); f.w = bf2f(q.w);
    } else { f.x = 0.f; f.y = 0.f; f.z = 0.f; f.w = 0.f; }
    *(float4*)&tile[r][cq] = f;
  }
  __syncthreads();
  int chl = c0 + tx;
  float kr[17];
  #pragma unroll
  for (int k = 0; k < 17; ++k) kr[k] = kern[chl*17 + k];
  int c = colbase + chl;
  float loc = 0.f;
  #pragma unroll
  for (int u = 0; u < 2; ++u) {
    u16x8 o;
    #pragma unroll
    for (int rr = 0; rr < 8; ++rr) {
      int r = ty*16 + u*8 + rr;
      float s = 0.0f;
      #pragma unroll
      for (int k = 0; k < 17; ++k) s = fmaf(kr[k], tile[r+k][tx], s);
      float val = tile[r+8][tx] + s;
      loc += val;
      o[rr] = f2bf(val);
    }
    int nn = n0 + ty*16 + u*8;
    *(u16x8*)(hF + ((((size_t)(nn>>5))*128 + (c>>4))*64 + ((nn>>3)&3)*16 + (c&15))*8) = o;
  }
  psum[ty][tx] = loc;
  __syncthreads();
  if (t < 64)
    atomicAdd(&hsum[colbase + c0 + t], psum[0][t]+psum[1][t]+psum[2][t]+psum[3][t]);
}

// qk dwconv (32-row): writes Eqk (row-major), Eq0, Ek2 (row-major), EqkF (fragment). grid (2, N/32)
__global__ __launch_bounds__(256) void dwconv_qk(
    const u16* __restrict__ xin, const float* __restrict__ kern,
    const float* __restrict__ osg, const float* __restrict__ osb,
    u16* __restrict__ Eqk, u16* __restrict__ Eq0, u16* __restrict__ Ek2,
    u16* __restrict__ EqkF, int N)
{
  __shared__ float tile[48][64];
  int c0 = blockIdx.x * 64;
  int n0 = blockIdx.y * 32;
  int t = threadIdx.x;
  int tx = t & 63, ty = t >> 6;
  #pragma unroll
  for (int it = 0; it < 3; ++it) {
    int idx = t + it*256;
    int r = idx >> 4, cq = (idx & 15)*4;
    int gn = n0 - 8 + r;
    float4 f;
    if (gn >= 0 && gn < N) {
      ushort4 q = *(const ushort4*)(xin + (size_t)gn*128 + c0 + cq);
      f.x = bf2f(q.x); f.y = bf2f(q.y); f.z = bf2f(q.z); f.w = bf2f(q.w);
    } else { f.x = 0.f; f.y = 0.f; f.z = 0.f; f.w = 0.f; }
    *(float4*)&tile[r][cq] = f;
  }
  __syncthreads();
  int ch = c0 + tx;
  float kr[17];
  #pragma unroll
  for (int k = 0; k < 17; ++k) kr[k] = kern[ch*17 + k];
  float g0 = osg[ch], b0 = osb[ch];
  float g2 = osg[2*128+ch], b2 = osb[2*128+ch];
  float vals[8];
  #pragma unroll
  for (int rr = 0; rr < 8; ++rr) {
    int r = ty*8 + rr;
    float s = 0.0f;
    #pragma unroll
    for (int k = 0; k < 17; ++k) s = fmaf(kr[k], tile[r+k][tx], s);
    vals[rr] = tile[r+8][tx] + s;
    size_t gi = (size_t)(n0 + r)*128 + ch;
    Eqk[gi] = f2bf(vals[rr]);
    Eq0[gi] = f2bf(fmaf(vals[rr], g0, b0));
    Ek2[gi] = f2bf(fmaf(vals[rr], g2, b2));
  }
  u16x8 o;
  #pragma unroll
  for (int rr = 0; rr < 8; ++rr) o[rr] = f2bf(vals[rr]);
  *(u16x8*)(EqkF + ((((size_t)(n0>>5))*8 + (ch>>4))*64 + ty*16 + (ch&15))*8) = o;
}

// final conv, 64-row tiles: out = resid + x + conv(x). grid (8, N/64)
__global__ __launch_bounds__(256) void dwconv_final64(
    const u16* __restrict__ xin, const float* __restrict__ kern,
    const float* __restrict__ resid, float* __restrict__ y, int N)
{
  __shared__ float tile[80][64];
  int c0 = blockIdx.x * 64;
  int n0 = blockIdx.y * 64;
  int t = threadIdx.x;
  int tx = t & 63, ty = t >> 6;
  #pragma unroll
  for (int it = 0; it < 5; ++it) {
    int idx = t + it*256;
    int r = idx >> 4, cq = (idx & 15)*4;
    int gn = n0 - 8 + r;
    float4 f;
    if (gn >= 0 && gn < N) {
      ushort4 q = *(const ushort4*)(xin + (size_t)gn*512 + c0 + cq);
      f.x = bf2f(q.x); f.y = bf2f(q.y); f.z = bf2f(q.z); f.w = bf2f(q.w);
    } else { f.x = 0.f; f.y = 0.f; f.z = 0.f; f.w = 0.f; }
    *(float4*)&tile[r][cq] = f;
  }
  __syncthreads();
  int ch = c0 + tx;
  float kr[17];
  #pragma unroll
  for (int k = 0; k < 17; ++k) kr[k] = kern[ch*17 + k];
  #pragma unroll
  for (int rr = 0; rr < 16; ++rr) {
    int r = ty*16 + rr;
    float s = 0.0f;
    #pragma unroll
    for (int k = 0; k < 17; ++k) s = fmaf(kr[k], tile[r+k][tx], s);
    size_t gi = (size_t)(n0 + r)*512 + ch;
    y[gi] = resid[gi] + tile[r+8][tx] + s;
  }
}

__global__ __launch_bounds__(256) void ln1024_kernel(u16* __restrict__ buf)
{
  long long n = blockIdx.x;
  ushort4* p = (ushort4*)(buf + n*1024) + threadIdx.x;
  ushort4 q = *p;
  float a = bf2f(q.x), b = bf2f(q.y), c = bf2f(q.z), d = bf2f(q.w);
  float s = a+b+c+d;
  float ss = fmaf(a,a, fmaf(b,b, fmaf(c,c, d*d)));
  float2 r = blockReduce2(s, ss);
  float mu = r.x * (1.0f/1024.0f);
  float var = r.y * (1.0f/1024.0f) - mu*mu;
  float rs = rsqrtf(var + 1e-5f);
  q.x = f2bf((a-mu)*rs); q.y = f2bf((b-mu)*rs);
  q.z = f2bf((c-mu)*rs); q.w = f2bf((d-mu)*rs);
  *p = q;
}

// ---------------- host launcher ----------------

extern "C" void kernel_launch(void* const* d_in, const int* in_sizes, int n_in,
                              void* d_out, int out_size, void* d_ws, size_t ws_size,
                              hipStream_t stream)
{
  const float* x        = (const float*)d_in[0];
  const float* th_ln_g  = (const float*)d_in[2];
  const float* th_ln_b  = (const float*)d_in[3];
  const float* th_w     = (const float*)d_in[4];
  const float* th_b     = (const float*)d_in[5];
  const float* th_conv  = (const float*)d_in[6];
  const float* qk_ln_g  = (const float*)d_in[7];
  const float* qk_ln_b  = (const float*)d_in[8];
  const float* qk_w     = (const float*)d_in[9];
  const float* qk_b     = (const float*)d_in[10];
  const float* qk_conv  = (const float*)d_in[11];
  const float* osg      = (const float*)d_in[12];
  const float* osb      = (const float*)d_in[13];
  const float* out_ln_g = (const float*)d_in[14];
  const float* out_ln_b = (const float*)d_in[15];
  const float* out_w    = (const float*)d_in[16];
  const float* out_b    = (const float*)d_in[17];
  const float* out_conv = (const float*)d_in[18];

  const int N = in_sizes[0] / 512;          // 16384
  const float inv_n = 1.0f / (float)N;
  const int G = N / GSZ;                    // 64
  char* wsb = (char*)d_ws;

  // ---- workspace layout (bytes), lifetime-aliased ----
  // hF [0, 67.1M) ; T2/Hpre [67.1, 100.7) ; region C [100.7, 117.4):
  //   nx (phase 1) -> {EqkF@0, Eq0@+N*256e, Ek2@+N*384e} -> attn@0 -> outtmp@0
  // Eqk [117.4, 121.6) ; Fraw-region (Dqk alias) [121.6, 125.8) ; weights after.
  size_t o_hF   = 0;
  size_t o_T2   = o_hF  + (size_t)N*2048*2;
  size_t o_C    = o_T2  + (size_t)N*1024*2;
  size_t o_eqk  = o_C   + (size_t)N*512*2;
  size_t o_fr   = o_eqk + (size_t)N*128*2;
  size_t o_wth  = o_fr  + (size_t)N*128*2;
  size_t o_wqk  = o_wth + (size_t)2048*512*2;
  size_t o_wout = o_wqk + (size_t)128*512*2;
  size_t o_bth  = o_wout+ (size_t)1024*512*2;
  size_t o_bqk  = o_bth + 2048*4;
  size_t o_bout = o_bqk + 128*4;
  size_t o_hsum = o_bout + 512*4;
  size_t required = o_hsum + 2048*4;
  if (ws_size < required) return;

  u16*   hF   = (u16*)(wsb + o_hF);
  u16*   T2   = (u16*)(wsb + o_T2);
  u16*   Hpre = T2;                        // alias: Hpre dead before quadlin writes T2
  u16*   Cu   = (u16*)(wsb + o_C);
  u16*   nx   = Cu;                        // phase 1
  u16*   EqkF = Cu;                        // after nx dead
  u16*   Eq0  = Cu + (size_t)N*256;
  u16*   Ek2  = Cu + (size_t)N*384;
  u16*   attn = Cu;                        // after EqkF dead (post-linkv)
  u16*   outtmp = Cu;                      // after quadlin
  u16*   Eqk  = (u16*)(wsb + o_eqk);
  u16*   Dqk  = (u16*)(wsb + o_fr);
  float* Fraw = (float*)(wsb + o_fr);                      // after Dqk dead
  u16*   FTg  = (u16*)(wsb + o_fr + (size_t)128*2048*4);
  float* cvec = (float*)(wsb + o_fr + (size_t)128*2048*4 + (size_t)2048*128*2);
  u16*   WthT = (u16*)(wsb + o_wth);
  u16*   WqkT = (u16*)(wsb + o_wqk);
  u16*   WoutT= (u16*)(wsb + o_wout);
  float* Bth  = (float*)(wsb + o_bth);
  float* Bqk  = (float*)(wsb + o_bqk);
  float* Bout = (float*)(wsb + o_bout);
  float* hsum = (float*)(wsb + o_hsum);

  // ---- weight prep + zeros ----
  hipLaunchKernelGGL(fuse_wT_kernel, dim3(16, 64), dim3(256), 0, stream, th_ln_g, th_w, WthT, 512, 2048);
  hipLaunchKernelGGL(fuse_wT_kernel, dim3(16, 4),  dim3(256), 0, stream, qk_ln_g, qk_w, WqkT, 512, 128);
  hipLaunchKernelGGL(fuse_wT_kernel, dim3(32, 16), dim3(256), 0, stream, out_ln_g, out_w, WoutT, 1024, 512);
  hipLaunchKernelGGL(copy_bias_kernel, dim3(8), dim3(256), 0, stream, th_b, Bth, 2048);
  hipLaunchKernelGGL(copy_bias_kernel, dim3(1), dim3(256), 0, stream, qk_b, Bqk, 128);
  hipLaunchKernelGGL(copy_bias_kernel, dim3(2), dim3(256), 0, stream, out_b, Bout, 512);
  hipLaunchKernelGGL(fuse_b_acc, dim3(8, 8),  dim3(256), 0, stream, th_ln_b,  th_w,  Bth, 512, 2048);
  hipLaunchKernelGGL(fuse_b_acc, dim3(1, 8),  dim3(256), 0, stream, qk_ln_b,  qk_w,  Bqk, 512, 128);
  hipLaunchKernelGGL(fuse_b_acc, dim3(2, 16), dim3(256), 0, stream, out_ln_b, out_w, Bout, 1024, 512);
  hipLaunchKernelGGL(zero_kernel, dim3(8), dim3(256), 0, stream, hsum, 2048LL);

  // ---- token shift + LN core (nx in region C) ----
  hipLaunchKernelGGL(shift_ln_kernel, dim3(N), dim3(256), 0, stream, x, nx, N);

  // ---- th branch, 2 super-chunks of 1024 cols: GEMM -> Hpre (T2 region), conv -> hF + hsum ----
  for (int sc = 0; sc < 2; ++sc) {
    hipLaunchKernelGGL(gemm_mfma_silu, dim3(8, N/128), dim3(256), 0, stream,
                       nx, 512, WthT, 512, sc*1024, Hpre, 1024, Bth, 512);
    hipLaunchKernelGGL(dwconv_hf64, dim3(16, N/64), dim3(256), 0, stream,
                       Hpre, 1024, th_conv + (size_t)sc*1024*17, hF, sc*1024, hsum, N);
  }

  // ---- qk branch: GEMM -> Dqk; conv -> Eqk + Eq0/Ek2 + EqkF (nx dead after qk GEMM) ----
  hipLaunchKernelGGL(gemm_mfma_silu, dim3(1, N/128), dim3(256), 0, stream,
                     nx, 512, WqkT, 512, 0, Dqk, 128, Bqk, 512);
  hipLaunchKernelGGL(dwconv_qk, dim3(2, N/32), dim3(256), 0, stream,
                     Dqk, qk_conv, osg, osb, Eqk, Eq0, Ek2, EqkF, N);

  // ---- linear attention kv summary (Dqk dead -> Fraw) ----
  hipLaunchKernelGGL(zero_kernel, dim3(1024), dim3(256), 0, stream, Fraw, (long long)128*2048);
  hipLaunchKernelGGL(linkv_mfma, dim3(32, 16), dim3(256), 0, stream, EqkF, hF, Fraw, N);
  hipLaunchKernelGGL(fconv_kernel, dim3(8), dim3(256), 0, stream, Fraw, osg, osb, hsum, inv_n, FTg, cvec);

  // ---- quadratic attention scores (EqkF dead -> attn) ----
  hipLaunchKernelGGL(score_mfma2, dim3(2, 2, G), dim3(256), 0, stream, Eq0, Ek2, attn);

  // ---- fused quad + lin + gate -> T2 (Hpre dead) ----
  hipLaunchKernelGGL(quadlin_mfma, dim3(2*G*16), dim3(256), 0, stream,
                     attn, hF, Eqk, FTg, cvec, T2);

  // ---- out branch ----
  hipLaunchKernelGGL(ln1024_kernel, dim3(N), dim3(256), 0, stream, T2);
  hipLaunchKernelGGL(gemm_mfma_silu, dim3(4, N/128), dim3(256), 0, stream,
                     T2, 1024, WoutT, 1024, 0, outtmp, 512, Bout, 1024);
  hipLaunchKernelGGL(dwconv_final64, dim3(8, N/64), dim3(256), 0, stream,
                     outtmp, out_conv, x, (float*)d_out, N);
}

// Round 12
// 383.185 us; speedup vs baseline: 1.1269x; 1.0189x over previous
//
#include <hip/hip_runtime.h>
#include <math.h>

#define GSZ 256

typedef unsigned short u16;
typedef short bf16x8 __attribute__((ext_vector_type(8)));
typedef u16 u16x8 __attribute__((ext_vector_type(8)));
typedef float f32x4 __attribute__((ext_vector_type(4)));
#define MFMA16 __builtin_amdgcn_mfma_f32_16x16x32_bf16

// hF fragment layout: unit(n,c) = hF + (((n>>5)*NCC + (c>>4))*64 + ((n>>3)&3)*16 + (c&15))*8,
// elem n&7.  NCC = 128 for h (2048 cols), 8 for EqkF (128 cols).

__device__ __forceinline__ float bf2f(u16 u){
  union { unsigned int i; float f; } x; x.i = ((unsigned int)u) << 16; return x.f;
}
__device__ __forceinline__ u16 f2bf(float f){
  union { float ff; unsigned int i; } x; x.ff = f;
  unsigned int r = x.i + 0x7fffu + ((x.i >> 16) & 1u);
  return (u16)(r >> 16);
}
__device__ __forceinline__ float sigm(float x){ return 1.0f/(1.0f+__expf(-x)); }
__device__ __forceinline__ float siluf(float x){ return x/(1.0f+__expf(-x)); }

__device__ __forceinline__ void gload16(const void* g, void* l){
  __builtin_amdgcn_global_load_lds(
      (const __attribute__((address_space(1))) void*)g,
      (__attribute__((address_space(3))) void*)l, 16, 0, 0);
}

__device__ __forceinline__ float2 blockReduce2(float s, float ss){
  __shared__ float red[8];
  #pragma unroll
  for (int off=32; off>0; off>>=1){
    s  += __shfl_down(s, off, 64);
    ss += __shfl_down(ss, off, 64);
  }
  int lane = threadIdx.x & 63, wid = threadIdx.x >> 6;
  if (lane==0){ red[wid]=s; red[4+wid]=ss; }
  __syncthreads();
  float2 r;
  r.x = red[0]+red[1]+red[2]+red[3];
  r.y = red[4]+red[5]+red[6]+red[7];
  return r;
}

// ---------------- small prep kernels ----------------

__global__ __launch_bounds__(256) void shift_ln_kernel(
    const float* __restrict__ x, u16* __restrict__ out, int N)
{
  int n = blockIdx.x;
  int t = threadIdx.x;
  float v0 = (n > 0) ? x[(long long)(n-1)*512 + t] : 0.0f;
  float v1 = x[(long long)n*512 + 256 + t];
  float2 r = blockReduce2(v0+v1, fmaf(v0,v0,v1*v1));
  float mu = r.x * (1.0f/512.0f);
  float var = r.y * (1.0f/512.0f) - mu*mu;
  float rs = rsqrtf(var + 1e-5f);
  long long base = (long long)n*512;
  out[base + t]       = f2bf((v0-mu)*rs);
  out[base + 256 + t] = f2bf((v1-mu)*rs);
}

__global__ __launch_bounds__(256) void fuse_wT_kernel(
    const float* __restrict__ g, const float* __restrict__ w,
    u16* __restrict__ wT, int K, int Nn)
{
  __shared__ float sL[32][33];
  int k0 = blockIdx.x*32, n0 = blockIdx.y*32;
  int t = threadIdx.x;
  int r = t >> 3, cq = t & 7;
  float4 v = *(const float4*)(w + (size_t)(k0+r)*Nn + n0 + cq*4);
  float gg = g[k0+r];
  sL[r][cq*4+0] = v.x*gg; sL[r][cq*4+1] = v.y*gg;
  sL[r][cq*4+2] = v.z*gg; sL[r][cq*4+3] = v.w*gg;
  __syncthreads();
  ushort4 o;
  o.x = f2bf(sL[cq*4+0][r]); o.y = f2bf(sL[cq*4+1][r]);
  o.z = f2bf(sL[cq*4+2][r]); o.w = f2bf(sL[cq*4+3][r]);
  *(ushort4*)(wT + (size_t)(n0+r)*K + k0 + cq*4) = o;
}

__global__ void copy_bias_kernel(const float* __restrict__ bias, float* __restrict__ bout, int Nn){
  int i = blockIdx.x*256 + threadIdx.x;
  if (i < Nn) bout[i] = bias[i];
}

__global__ __launch_bounds__(256) void fuse_b_acc(
    const float* __restrict__ bln, const float* __restrict__ w,
    float* __restrict__ bout, int K, int Nn)
{
  int n = blockIdx.x*256 + threadIdx.x;
  int k0 = blockIdx.y*64;
  if (n >= Nn) return;
  float acc = 0.f;
  #pragma unroll
  for (int k = 0; k < 64; ++k)
    acc = fmaf(bln[k0+k], w[(size_t)(k0+k)*Nn + n], acc);
  atomicAdd(&bout[n], acc);
}

__global__ void zero_kernel(float* __restrict__ p, long long total){
  long long i = (long long)blockIdx.x*256 + threadIdx.x;
  if (i < total) p[i] = 0.0f;
}

// ---------------- MFMA kernels (chunk-linear LDS + global_load_lds) --------------
// LDS chunk = 64 units x 16B; unit l of chunk = fragment of lane l.
// MFMA frags: A row=l&15 k=(l>>4)*8+j ; B col=l&15 ; D col=l&15 row=(l>>4)*4+i.
// Depth-2 pipeline: 3 buffers, tiles t+1,t+2 in flight, wait vmcnt(8) (per-wave).

// C = silu(A @ WT^T + bias).  BM=128, BN=128, BK=32.
__global__ __launch_bounds__(256) void gemm_mfma_silu(
    const u16* __restrict__ A, int lda,
    const u16* __restrict__ BT, int ldbt, int wtc0,
    u16* __restrict__ C, int ldc,
    const float* __restrict__ bias, int K)
{
  __shared__ u16 lds[3*16*512];
  int t = threadIdx.x;
  int lane = t & 63, wid = t >> 6;
  int wm = wid >> 1, wn = wid & 1;
  int lrow = lane & 15, kcL = lane >> 4;
  int bm = blockIdx.y*128, bn = blockIdx.x*128;
  const u16* gA0 = A + (size_t)(bm + wid*16 + lrow)*lda + kcL*8;
  const u16* gA1 = A + (size_t)(bm + (wid+4)*16 + lrow)*lda + kcL*8;
  const u16* gB0 = BT + (size_t)(wtc0 + bn + wid*16 + lrow)*ldbt + kcL*8;
  const u16* gB1 = BT + (size_t)(wtc0 + bn + (wid+4)*16 + lrow)*ldbt + kcL*8;
  f32x4 acc[4][4] = {};
  int nt = K >> 5;
  auto issue = [&](int ti, u16* b){
    int k1 = ti << 5;
    gload16(gA0 + k1, b + (size_t)wid*512);
    gload16(gA1 + k1, b + (size_t)(wid+4)*512);
    gload16(gB0 + k1, b + (size_t)(8+wid)*512);
    gload16(gB1 + k1, b + (size_t)(12+wid)*512);
  };
  issue(0, lds);
  if (nt > 1) issue(1, lds + 8192);
  for (int ti = 0; ti < nt; ++ti) {
    if (ti + 2 < nt) {
      issue(ti + 2, lds + (size_t)((ti+2)%3)*8192);
      asm volatile("s_waitcnt vmcnt(8)" ::: "memory");
    } else if (ti + 1 < nt) {
      asm volatile("s_waitcnt vmcnt(4)" ::: "memory");
    } else {
      asm volatile("s_waitcnt vmcnt(0)" ::: "memory");
    }
    __builtin_amdgcn_s_barrier();
    asm volatile("" ::: "memory");
    const bf16x8* L = (const bf16x8*)(lds + (size_t)(ti%3)*8192);
    bf16x8 af[4], bfr[4];
    #pragma unroll
    for (int mr = 0; mr < 4; ++mr) af[mr] = L[(wm*4+mr)*64 + lane];
    #pragma unroll
    for (int nr = 0; nr < 4; ++nr) bfr[nr] = L[(8 + wn*4+nr)*64 + lane];
    #pragma unroll
    for (int mr = 0; mr < 4; ++mr)
      #pragma unroll
      for (int nr = 0; nr < 4; ++nr)
        acc[mr][nr] = MFMA16(af[mr], bfr[nr], acc[mr][nr], 0, 0, 0);
    asm volatile("" ::: "memory");
    __builtin_amdgcn_s_barrier();
  }
  #pragma unroll
  for (int mr = 0; mr < 4; ++mr)
    #pragma unroll
    for (int nr = 0; nr < 4; ++nr) {
      int col = bn + wn*64 + nr*16 + lrow;
      float bs = bias[wtc0 + col];
      #pragma unroll
      for (int i = 0; i < 4; ++i) {
        int row = bm + wm*64 + mr*16 + kcL*4 + i;
        C[(size_t)row*ldc + col] = f2bf(siluf(acc[mr][nr][i] + bs));
      }
    }
}

// attn = relu(Eq0 @ Ek2^T / GS)^2 per group — depth-2 GEMM. grid (2, 2, G)
__global__ __launch_bounds__(256) void score_mfma2(
    const u16* __restrict__ Eq0, const u16* __restrict__ Ek2,
    u16* __restrict__ attn)
{
  __shared__ u16 lds[3*16*512];
  int t = threadIdx.x;
  int lane = t & 63, wid = t >> 6;
  int wm = wid >> 1, wn = wid & 1;
  int lrow = lane & 15, kcL = lane >> 4;
  int g = blockIdx.z;
  int bm = blockIdx.y*128, bn = blockIdx.x*128;
  size_t rowbase = (size_t)g * GSZ;
  const u16* gA0 = Eq0 + (rowbase + bm + wid*16 + lrow)*128 + kcL*8;
  const u16* gA1 = Eq0 + (rowbase + bm + (wid+4)*16 + lrow)*128 + kcL*8;
  const u16* gB0 = Ek2 + (rowbase + bn + wid*16 + lrow)*128 + kcL*8;
  const u16* gB1 = Ek2 + (rowbase + bn + (wid+4)*16 + lrow)*128 + kcL*8;
  f32x4 acc[4][4] = {};
  auto issue = [&](int ti, u16* b){
    int k1 = ti << 5;
    gload16(gA0 + k1, b + (size_t)wid*512);
    gload16(gA1 + k1, b + (size_t)(wid+4)*512);
    gload16(gB0 + k1, b + (size_t)(8+wid)*512);
    gload16(gB1 + k1, b + (size_t)(12+wid)*512);
  };
  issue(0, lds);
  issue(1, lds + 8192);
  for (int ti = 0; ti < 4; ++ti) {
    if (ti + 2 < 4) {
      issue(ti + 2, lds + (size_t)((ti+2)%3)*8192);
      asm volatile("s_waitcnt vmcnt(8)" ::: "memory");
    } else if (ti + 1 < 4) {
      asm volatile("s_waitcnt vmcnt(4)" ::: "memory");
    } else {
      asm volatile("s_waitcnt vmcnt(0)" ::: "memory");
    }
    __builtin_amdgcn_s_barrier();
    asm volatile("" ::: "memory");
    const bf16x8* L = (const bf16x8*)(lds + (size_t)(ti%3)*8192);
    bf16x8 af[4], bfr[4];
    #pragma unroll
    for (int mr = 0; mr < 4; ++mr) af[mr] = L[(wm*4+mr)*64 + lane];
    #pragma unroll
    for (int nr = 0; nr < 4; ++nr) bfr[nr] = L[(8 + wn*4+nr)*64 + lane];
    #pragma unroll
    for (int mr = 0; mr < 4; ++mr)
      #pragma unroll
      for (int nr = 0; nr < 4; ++nr)
        acc[mr][nr] = MFMA16(af[mr], bfr[nr], acc[mr][nr], 0, 0, 0);
    asm volatile("" ::: "memory");
    __builtin_amdgcn_s_barrier();
  }
  #pragma unroll
  for (int mr = 0; mr < 4; ++mr)
    #pragma unroll
    for (int nr = 0; nr < 4; ++nr) {
      int col = bn + wn*64 + nr*16 + lrow;
      #pragma unroll
      for (int i = 0; i < 4; ++i) {
        int row = bm + wm*64 + mr*16 + kcL*4 + i;
        float s = fmaxf(acc[mr][nr][i] * (1.0f/GSZ), 0.0f);
        attn[(rowbase + row)*GSZ + col] = f2bf(s*s);
      }
    }
}

// Fraw[d][e] += sum_n EqkF(n,d) * hF(n,e) — pure gload dbuf GEMM. grid (32, 16)
__global__ __launch_bounds__(256) void linkv_mfma(
    const u16* __restrict__ EqkF, const u16* __restrict__ hF,
    float* __restrict__ Fraw, int N)
{
  __shared__ u16 lds[2*12*512];
  int t = threadIdx.x;
  int lane = t & 63, wid = t >> 6;
  int wm = wid >> 1, wn = wid & 1;
  int lrow = lane & 15, kcL = lane >> 4;
  int e0 = blockIdx.x * 64;
  int nkt = (N / gridDim.y) >> 5;
  size_t kt0 = (size_t)blockIdx.y * nkt;
  f32x4 acc[4][2] = {};
  auto issue = [&](int kt, u16* b) {
    size_t ktile = kt0 + kt;
    gload16(EqkF + ((ktile*8 + wid)*64 + lane)*8,           b + (size_t)wid*512);
    gload16(EqkF + ((ktile*8 + wid+4)*64 + lane)*8,         b + (size_t)(wid+4)*512);
    gload16(hF + ((ktile*128 + (e0>>4) + wid)*64 + lane)*8, b + (size_t)(8+wid)*512);
  };
  issue(0, lds);
  int cur = 0;
  for (int ti = 0; ti < nkt; ++ti) {
    if (ti + 1 < nkt) {
      issue(ti + 1, lds + (size_t)(cur^1)*6144);
      asm volatile("s_waitcnt vmcnt(3)" ::: "memory");
    } else {
      asm volatile("s_waitcnt vmcnt(0)" ::: "memory");
    }
    __builtin_amdgcn_s_barrier();
    asm volatile("" ::: "memory");
    const bf16x8* L = (const bf16x8*)(lds + (size_t)cur*6144);
    bf16x8 af[4], bfr[2];
    #pragma unroll
    for (int mr = 0; mr < 4; ++mr) af[mr] = L[(wm*4+mr)*64 + lane];
    #pragma unroll
    for (int nr = 0; nr < 2; ++nr) bfr[nr] = L[(8 + wn*2+nr)*64 + lane];
    #pragma unroll
    for (int mr = 0; mr < 4; ++mr)
      #pragma unroll
      for (int nr = 0; nr < 2; ++nr)
        acc[mr][nr] = MFMA16(af[mr], bfr[nr], acc[mr][nr], 0, 0, 0);
    asm volatile("" ::: "memory");
    __builtin_amdgcn_s_barrier();
    cur ^= 1;
  }
  #pragma unroll
  for (int mr = 0; mr < 4; ++mr)
    #pragma unroll
    for (int nr = 0; nr < 2; ++nr) {
      int e = e0 + wn*32 + nr*16 + lrow;
      #pragma unroll
      for (int i = 0; i < 4; ++i) {
        int d = wm*64 + mr*16 + kcL*4 + i;
        atomicAdd(&Fraw[(size_t)d*2048 + e], acc[mr][nr][i]);
      }
    }
}

// F = inv_n*(g3[d]*Fraw + b3[d]*hsum[e]); FTg[e][d] = g1[d]*F ; cvec[e] = sum_d b1[d]*F
__global__ __launch_bounds__(256) void fconv_kernel(
    const float* __restrict__ Fraw, const float* __restrict__ osg, const float* __restrict__ osb,
    const float* __restrict__ hsum, float inv_n,
    u16* __restrict__ FTg, float* __restrict__ cvec)
{
  __shared__ float g1s[128], b1s[128], g3s[128], b3s[128];
  int t = threadIdx.x;
  if (t < 128) { g1s[t] = osg[128+t]; b1s[t] = osb[128+t];
                 g3s[t] = osg[3*128+t]; b3s[t] = osb[3*128+t]; }
  __syncthreads();
  int e = blockIdx.x*256 + t;
  float hs = hsum[e];
  float c = 0.f;
  for (int d = 0; d < 128; ++d) {
    float f = inv_n * fmaf(g3s[d], Fraw[(size_t)d*2048 + e], b3s[d]*hs);
    c = fmaf(b1s[d], f, c);
    FTg[(size_t)e*128 + d] = f2bf(g1s[d] * f);
  }
  cvec[e] = c;
}

// fused quad+lin attention + gate. Depth-2, 3 buffers, counted vmcnt. grid 2048.
__global__ __launch_bounds__(256) void quadlin_mfma(
    const u16* __restrict__ attn, const u16* __restrict__ hF,
    const u16* __restrict__ eqk, const u16* __restrict__ FTg,
    const float* __restrict__ cvec, u16* __restrict__ T2)
{
  __shared__ u16 lds[3*16*512];
  int bid = blockIdx.x;
  int wgid = (bid & 7)*256 + (bid >> 3);
  int g = wgid >> 5;
  int rem = wgid & 31;
  int bm = (rem >> 4) * 128;
  int cb = (rem & 15) * 64;
  int t = threadIdx.x;
  int lane = t & 63, wid = t >> 6;
  int wm = wid >> 1, wn = wid & 1;
  int lrow = lane & 15, kcL = lane >> 4;
  size_t rowbase = (size_t)g * GSZ;
  f32x4 accV[4][2] = {}, accU[4][2] = {};
  const u16* gA0q = attn + (rowbase + bm + wid*16 + lrow)*GSZ + kcL*8;
  const u16* gA1q = attn + (rowbase + bm + (wid+4)*16 + lrow)*GSZ + kcL*8;
  const u16* gA0l = eqk + (rowbase + bm + wid*16 + lrow)*128 + kcL*8;
  const u16* gA1l = eqk + (rowbase + bm + (wid+4)*16 + lrow)*128 + kcL*8;
  const u16* gBVl = FTg + (size_t)(cb + wid*16 + lrow)*128 + kcL*8;
  const u16* gBUl = FTg + (size_t)(1024 + cb + wid*16 + lrow)*128 + kcL*8;
  auto issue = [&](int ti, u16* b) {
    if (ti < 8) {
      int k0 = ti << 5;
      size_t ktile = (size_t)g*8 + ti;
      gload16(gA0q + k0, b + (size_t)wid*512);
      gload16(gA1q + k0, b + (size_t)(wid+4)*512);
      gload16(hF + ((ktile*128 + (cb>>4) + wid)*64 + lane)*8,      b + (size_t)(8+wid)*512);
      gload16(hF + ((ktile*128 + 64 + (cb>>4) + wid)*64 + lane)*8, b + (size_t)(12+wid)*512);
    } else {
      int k0 = (ti - 8) << 5;
      gload16(gA0l + k0, b + (size_t)wid*512);
      gload16(gA1l + k0, b + (size_t)(wid+4)*512);
      gload16(gBVl + k0, b + (size_t)(8+wid)*512);
      gload16(gBUl + k0, b + (size_t)(12+wid)*512);
    }
  };
  issue(0, lds);
  issue(1, lds + 8192);
  for (int ti = 0; ti < 12; ++ti) {
    if (ti + 2 < 12) {
      issue(ti + 2, lds + (size_t)((ti+2)%3)*8192);
      asm volatile("s_waitcnt vmcnt(8)" ::: "memory");
    } else if (ti + 1 < 12) {
      asm volatile("s_waitcnt vmcnt(4)" ::: "memory");
    } else {
      asm volatile("s_waitcnt vmcnt(0)" ::: "memory");
    }
    __builtin_amdgcn_s_barrier();
    asm volatile("" ::: "memory");
    const bf16x8* L = (const bf16x8*)(lds + (size_t)(ti%3)*8192);
    bf16x8 af[4], bv[2], bu[2];
    #pragma unroll
    for (int mr = 0; mr < 4; ++mr) af[mr] = L[(wm*4+mr)*64 + lane];
    #pragma unroll
    for (int nr = 0; nr < 2; ++nr) { bv[nr] = L[(8 + wn*2+nr)*64 + lane];
                                     bu[nr] = L[(12 + wn*2+nr)*64 + lane]; }
    #pragma unroll
    for (int mr = 0; mr < 4; ++mr)
      #pragma unroll
      for (int nr = 0; nr < 2; ++nr) {
        accV[mr][nr] = MFMA16(af[mr], bv[nr], accV[mr][nr], 0, 0, 0);
        accU[mr][nr] = MFMA16(af[mr], bu[nr], accU[mr][nr], 0, 0, 0);
      }
    asm volatile("" ::: "memory");
    __builtin_amdgcn_s_barrier();
  }
  #pragma unroll
  for (int mr = 0; mr < 4; ++mr)
    #pragma unroll
    for (int nr = 0; nr < 2; ++nr) {
      int c = cb + wn*32 + nr*16 + lrow;
      float cV = cvec[c], cU = cvec[1024 + c];
      int np = bm + wm*64 + mr*16 + kcL*4;
      size_t ktile = (size_t)g*8 + (np>>5);
      int lofs = ((np>>3)&3)*16 + (c&15);
      int eo = np & 7;
      ushort4 vq = *(const ushort4*)(hF + ((ktile*128 + (c>>4))*64 + lofs)*8 + eo);
      ushort4 uq = *(const ushort4*)(hF + ((ktile*128 + 64 + (c>>4))*64 + lofs)*8 + eo);
      float vv[4] = {bf2f(vq.x), bf2f(vq.y), bf2f(vq.z), bf2f(vq.w)};
      float uu[4] = {bf2f(uq.x), bf2f(uq.y), bf2f(uq.z), bf2f(uq.w)};
      #pragma unroll
      for (int i = 0; i < 4; ++i) {
        float av = accV[mr][nr][i] + cV;
        float au = accU[mr][nr][i] + cU;
        T2[(rowbase + np + i)*1024 + c] = f2bf(au * vv[i] * sigm(av * uu[i]));
      }
    }
}

// ---------------- conv / norm kernels ----------------

// th-branch depthwise conv, 64-row tiles -> hF + hsum. grid (cols/64, N/64)
__global__ __launch_bounds__(256) void dwconv_hf64(
    const u16* __restrict__ xin, int ldin, const float* __restrict__ kern,
    u16* __restrict__ hF, int colbase, float* __restrict__ hsum, int N)
{
  __shared__ float tile[80][64];
  __shared__ float psum[4][64];
  int c0 = blockIdx.x * 64;
  int n0 = blockIdx.y * 64;
  int t = threadIdx.x;
  int tx = t & 63, ty = t >> 6;
  #pragma unroll
  for (int it = 0; it < 5; ++it) {
    int idx = t + it*256;
    int r = idx >> 4, cq = (idx & 15)*4;
    int gn = n0 - 8 + r;
    float4 f;
    if (gn >= 0 && gn < N) {
      ushort4 q = *(const ushort4*)(xin + (size_t)gn*ldin + c0 + cq);
      f.x = bf2f(q.x); f.y = bf2f(q.y); f.z = bf2f(q.z); f.w = bf2f(q.w);
    } else { f.x = 0.f; f.y = 0.f; f.z = 0.f; f.w = 0.f; }
    *(float4*)&tile[r][cq] = f;
  }
  __syncthreads();
  int chl = c0 + tx;
  float kr[17];
  #pragma unroll
  for (int k = 0; k < 17; ++k) kr[k] = kern[chl*17 + k];
  int c = colbase + chl;
  float loc = 0.f;
  #pragma unroll
  for (int u = 0; u < 2; ++u) {
    u16x8 o;
    #pragma unroll
    for (int rr = 0; rr < 8; ++rr) {
      int r = ty*16 + u*8 + rr;
      float s = 0.0f;
      #pragma unroll
      for (int k = 0; k < 17; ++k) s = fmaf(kr[k], tile[r+k][tx], s);
      float val = tile[r+8][tx] + s;
      loc += val;
      o[rr] = f2bf(val);
    }
    int nn = n0 + ty*16 + u*8;
    *(u16x8*)(hF + ((((size_t)(nn>>5))*128 + (c>>4))*64 + ((nn>>3)&3)*16 + (c&15))*8) = o;
  }
  psum[ty][tx] = loc;
  __syncthreads();
  if (t < 64)
    atomicAdd(&hsum[colbase + c0 + t], psum[0][t]+psum[1][t]+psum[2][t]+psum[3][t]);
}

// qk dwconv (32-row): writes Eqk (row-major), Eq0, Ek2 (row-major), EqkF (fragment). grid (2, N/32)
__global__ __launch_bounds__(256) void dwconv_qk(
    const u16* __restrict__ xin, const float* __restrict__ kern,
    const float* __restrict__ osg, const float* __restrict__ osb,
    u16* __restrict__ Eqk, u16* __restrict__ Eq0, u16* __restrict__ Ek2,
    u16* __restrict__ EqkF, int N)
{
  __shared__ float tile[48][64];
  int c0 = blockIdx.x * 64;
  int n0 = blockIdx.y * 32;
  int t = threadIdx.x;
  int tx = t & 63, ty = t >> 6;
  #pragma unroll
  for (int it = 0; it < 3; ++it) {
    int idx = t + it*256;
    int r = idx >> 4, cq = (idx & 15)*4;
    int gn = n0 - 8 + r;
    float4 f;
    if (gn >= 0 && gn < N) {
      ushort4 q = *(const ushort4*)(xin + (size_t)gn*128 + c0 + cq);
      f.x = bf2f(q.x); f.y = bf2f(q.y); f.z = bf2f(q.z); f.w = bf2f(q.w);
    } else { f.x = 0.f; f.y = 0.f; f.z = 0.f; f.w = 0.f; }
    *(float4*)&tile[r][cq] = f;
  }
  __syncthreads();
  int ch = c0 + tx;
  float kr[17];
  #pragma unroll
  for (int k = 0; k < 17; ++k) kr[k] = kern[ch*17 + k];
  float g0 = osg[ch], b0 = osb[ch];
  float g2 = osg[2*128+ch], b2 = osb[2*128+ch];
  float vals[8];
  #pragma unroll
  for (int rr = 0; rr < 8; ++rr) {
    int r = ty*8 + rr;
    float s = 0.0f;
    #pragma unroll
    for (int k = 0; k < 17; ++k) s = fmaf(kr[k], tile[r+k][tx], s);
    vals[rr] = tile[r+8][tx] + s;
    size_t gi = (size_t)(n0 + r)*128 + ch;
    Eqk[gi] = f2bf(vals[rr]);
    Eq0[gi] = f2bf(fmaf(vals[rr], g0, b0));
    Ek2[gi] = f2bf(fmaf(vals[rr], g2, b2));
  }
  u16x8 o;
  #pragma unroll
  for (int rr = 0; rr < 8; ++rr) o[rr] = f2bf(vals[rr]);
  *(u16x8*)(EqkF + ((((size_t)(n0>>5))*8 + (ch>>4))*64 + ty*16 + (ch&15))*8) = o;
}

// final conv, 64-row tiles: out = resid + x + conv(x). grid (8, N/64)
__global__ __launch_bounds__(256) void dwconv_final64(
    const u16* __restrict__ xin, const float* __restrict__ kern,
    const float* __restrict__ resid, float* __restrict__ y, int N)
{
  __shared__ float tile[80][64];
  int c0 = blockIdx.x * 64;
  int n0 = blockIdx.y * 64;
  int t = threadIdx.x;
  int tx = t & 63, ty = t >> 6;
  #pragma unroll
  for (int it = 0; it < 5; ++it) {
    int idx = t + it*256;
    int r = idx >> 4, cq = (idx & 15)*4;
    int gn = n0 - 8 + r;
    float4 f;
    if (gn >= 0 && gn < N) {
      ushort4 q = *(const ushort4*)(xin + (size_t)gn*512 + c0 + cq);
      f.x = bf2f(q.x); f.y = bf2f(q.y); f.z = bf2f(q.z); f.w = bf2f(q.w);
    } else { f.x = 0.f; f.y = 0.f; f.z = 0.f; f.w = 0.f; }
    *(float4*)&tile[r][cq] = f;
  }
  __syncthreads();
  int ch = c0 + tx;
  float kr[17];
  #pragma unroll
  for (int k = 0; k < 17; ++k) kr[k] = kern[ch*17 + k];
  #pragma unroll
  for (int rr = 0; rr < 16; ++rr) {
    int r = ty*16 + rr;
    float s = 0.0f;
    #pragma unroll
    for (int k = 0; k < 17; ++k) s = fmaf(kr[k], tile[r+k][tx], s);
    size_t gi = (size_t)(n0 + r)*512 + ch;
    y[gi] = resid[gi] + tile[r+8][tx] + s;
  }
}

__global__ __launch_bounds__(256) void ln1024_kernel(u16* __restrict__ buf)
{
  long long n = blockIdx.x;
  ushort4* p = (ushort4*)(buf + n*1024) + threadIdx.x;
  ushort4 q = *p;
  float a = bf2f(q.x), b = bf2f(q.y), c = bf2f(q.z), d = bf2f(q.w);
  float s = a+b+c+d;
  float ss = fmaf(a,a, fmaf(b,b, fmaf(c,c, d*d)));
  float2 r = blockReduce2(s, ss);
  float mu = r.x * (1.0f/1024.0f);
  float var = r.y * (1.0f/1024.0f) - mu*mu;
  float rs = rsqrtf(var + 1e-5f);
  q.x = f2bf((a-mu)*rs); q.y = f2bf((b-mu)*rs);
  q.z = f2bf((c-mu)*rs); q.w = f2bf((d-mu)*rs);
  *p = q;
}

// ---------------- host launcher ----------------

extern "C" void kernel_launch(void* const* d_in, const int* in_sizes, int n_in,
                              void* d_out, int out_size, void* d_ws, size_t ws_size,
                              hipStream_t stream)
{
  const float* x        = (const float*)d_in[0];
  const float* th_ln_g  = (const float*)d_in[2];
  const float* th_ln_b  = (const float*)d_in[3];
  const float* th_w     = (const float*)d_in[4];
  const float* th_b     = (const float*)d_in[5];
  const float* th_conv  = (const float*)d_in[6];
  const float* qk_ln_g  = (const float*)d_in[7];
  const float* qk_ln_b  = (const float*)d_in[8];
  const float* qk_w     = (const float*)d_in[9];
  const float* qk_b     = (const float*)d_in[10];
  const float* qk_conv  = (const float*)d_in[11];
  const float* osg      = (const float*)d_in[12];
  const float* osb      = (const float*)d_in[13];
  const float* out_ln_g = (const float*)d_in[14];
  const float* out_ln_b = (const float*)d_in[15];
  const float* out_w    = (const float*)d_in[16];
  const float* out_b    = (const float*)d_in[17];
  const float* out_conv = (const float*)d_in[18];

  const int N = in_sizes[0] / 512;          // 16384
  const float inv_n = 1.0f / (float)N;
  const int G = N / GSZ;                    // 64
  char* wsb = (char*)d_ws;

  // ---- workspace layout (bytes), lifetime-aliased ----
  size_t o_hF   = 0;
  size_t o_T2   = o_hF  + (size_t)N*2048*2;
  size_t o_C    = o_T2  + (size_t)N*1024*2;
  size_t o_eqk  = o_C   + (size_t)N*512*2;
  size_t o_fr   = o_eqk + (size_t)N*128*2;
  size_t o_wth  = o_fr  + (size_t)N*128*2;
  size_t o_wqk  = o_wth + (size_t)2048*512*2;
  size_t o_wout = o_wqk + (size_t)128*512*2;
  size_t o_bth  = o_wout+ (size_t)1024*512*2;
  size_t o_bqk  = o_bth + 2048*4;
  size_t o_bout = o_bqk + 128*4;
  size_t o_hsum = o_bout + 512*4;
  size_t required = o_hsum + 2048*4;
  if (ws_size < required) return;

  u16*   hF   = (u16*)(wsb + o_hF);
  u16*   T2   = (u16*)(wsb + o_T2);
  u16*   Hpre = T2;
  u16*   Cu   = (u16*)(wsb + o_C);
  u16*   nx   = Cu;
  u16*   EqkF = Cu;
  u16*   Eq0  = Cu + (size_t)N*256;
  u16*   Ek2  = Cu + (size_t)N*384;
  u16*   attn = Cu;
  u16*   outtmp = Cu;
  u16*   Eqk  = (u16*)(wsb + o_eqk);
  u16*   Dqk  = (u16*)(wsb + o_fr);
  float* Fraw = (float*)(wsb + o_fr);
  u16*   FTg  = (u16*)(wsb + o_fr + (size_t)128*2048*4);
  float* cvec = (float*)(wsb + o_fr + (size_t)128*2048*4 + (size_t)2048*128*2);
  u16*   WthT = (u16*)(wsb + o_wth);
  u16*   WqkT = (u16*)(wsb + o_wqk);
  u16*   WoutT= (u16*)(wsb + o_wout);
  float* Bth  = (float*)(wsb + o_bth);
  float* Bqk  = (float*)(wsb + o_bqk);
  float* Bout = (float*)(wsb + o_bout);
  float* hsum = (float*)(wsb + o_hsum);

  // ---- weight prep + zeros ----
  hipLaunchKernelGGL(fuse_wT_kernel, dim3(16, 64), dim3(256), 0, stream, th_ln_g, th_w, WthT, 512, 2048);
  hipLaunchKernelGGL(fuse_wT_kernel, dim3(16, 4),  dim3(256), 0, stream, qk_ln_g, qk_w, WqkT, 512, 128);
  hipLaunchKernelGGL(fuse_wT_kernel, dim3(32, 16), dim3(256), 0, stream, out_ln_g, out_w, WoutT, 1024, 512);
  hipLaunchKernelGGL(copy_bias_kernel, dim3(8), dim3(256), 0, stream, th_b, Bth, 2048);
  hipLaunchKernelGGL(copy_bias_kernel, dim3(1), dim3(256), 0, stream, qk_b, Bqk, 128);
  hipLaunchKernelGGL(copy_bias_kernel, dim3(2), dim3(256), 0, stream, out_b, Bout, 512);
  hipLaunchKernelGGL(fuse_b_acc, dim3(8, 8),  dim3(256), 0, stream, th_ln_b,  th_w,  Bth, 512, 2048);
  hipLaunchKernelGGL(fuse_b_acc, dim3(1, 8),  dim3(256), 0, stream, qk_ln_b,  qk_w,  Bqk, 512, 128);
  hipLaunchKernelGGL(fuse_b_acc, dim3(2, 16), dim3(256), 0, stream, out_ln_b, out_w, Bout, 1024, 512);
  hipLaunchKernelGGL(zero_kernel, dim3(8), dim3(256), 0, stream, hsum, 2048LL);

  // ---- token shift + LN core ----
  hipLaunchKernelGGL(shift_ln_kernel, dim3(N), dim3(256), 0, stream, x, nx, N);

  // ---- th branch, 2 super-chunks of 1024 cols ----
  for (int sc = 0; sc < 2; ++sc) {
    hipLaunchKernelGGL(gemm_mfma_silu, dim3(8, N/128), dim3(256), 0, stream,
                       nx, 512, WthT, 512, sc*1024, Hpre, 1024, Bth, 512);
    hipLaunchKernelGGL(dwconv_hf64, dim3(16, N/64), dim3(256), 0, stream,
                       Hpre, 1024, th_conv + (size_t)sc*1024*17, hF, sc*1024, hsum, N);
  }

  // ---- qk branch ----
  hipLaunchKernelGGL(gemm_mfma_silu, dim3(1, N/128), dim3(256), 0, stream,
                     nx, 512, WqkT, 512, 0, Dqk, 128, Bqk, 512);
  hipLaunchKernelGGL(dwconv_qk, dim3(2, N/32), dim3(256), 0, stream,
                     Dqk, qk_conv, osg, osb, Eqk, Eq0, Ek2, EqkF, N);

  // ---- linear attention kv summary ----
  hipLaunchKernelGGL(zero_kernel, dim3(1024), dim3(256), 0, stream, Fraw, (long long)128*2048);
  hipLaunchKernelGGL(linkv_mfma, dim3(32, 16), dim3(256), 0, stream, EqkF, hF, Fraw, N);
  hipLaunchKernelGGL(fconv_kernel, dim3(8), dim3(256), 0, stream, Fraw, osg, osb, hsum, inv_n, FTg, cvec);

  // ---- quadratic attention scores ----
  hipLaunchKernelGGL(score_mfma2, dim3(2, 2, G), dim3(256), 0, stream, Eq0, Ek2, attn);

  // ---- fused quad + lin + gate -> T2 ----
  hipLaunchKernelGGL(quadlin_mfma, dim3(2*G*16), dim3(256), 0, stream,
                     attn, hF, Eqk, FTg, cvec, T2);

  // ---- out branch ----
  hipLaunchKernelGGL(ln1024_kernel, dim3(N), dim3(256), 0, stream, T2);
  hipLaunchKernelGGL(gemm_mfma_silu, dim3(4, N/128), dim3(256), 0, stream,
                     T2, 1024, WoutT, 1024, 0, outtmp, 512, Bout, 1024);
  hipLaunchKernelGGL(dwconv_final64, dim3(8, N/64), dim3(256), 0, stream,
                     outtmp, out_conv, x, (float*)d_out, N);
}